// Round 9
// baseline (433.849 us; speedup 1.0000x reference)
//
#include <hip/hip_runtime.h>
#include <stdint.h>

typedef unsigned short u16;
using us8   = __attribute__((ext_vector_type(8))) unsigned short;
using us4   = __attribute__((ext_vector_type(4))) unsigned short;
using bf16x8 = __attribute__((ext_vector_type(8))) __bf16;
using f32x4 = __attribute__((ext_vector_type(4))) float;

#define DEV static __device__ __forceinline__

DEV float bf2f(u16 u) { union { uint32_t i; float f; } v; v.i = (uint32_t)u << 16; return v.f; }
DEV u16 f2bf(float f) {
    union { float f; uint32_t i; } v; v.f = f;
    uint32_t u = v.i;
    return (u16)((u + 0x7FFFu + ((u >> 16) & 1u)) >> 16);
}

// async global->LDS 16B copy: lane l writes LDS at (uniform base) + l*16B.
DEV void async16(const u16* g, u16* ldsbase)
{
    __builtin_amdgcn_global_load_lds((const __attribute__((address_space(1))) void*)g,
                                     (__attribute__((address_space(3))) void*)ldsbase, 16, 0, 0);
}

// ---------------------------------------------------------------------------
// Fused dtype detection + mask expansion + param conversion: 18 blocks.
// Each block detects its tensor's dtype (flag), then: block 1 expands the
// mask to maskb; param blocks (paroff>=0) convert their (<=4096-elem) tensor
// into par[] directly. Replaces k_expand_mask + k_convert_params launches.
// ---------------------------------------------------------------------------
struct DetectArgs { const void* p[18]; int nw[18]; int paroff[18]; };

__global__ __launch_bounds__(256) void k_detect_all(DetectArgs a, int* flags,
                                                    float* maskb, float* par)
{
    const int b = blockIdx.x;
    const int t = threadIdx.x;
    __shared__ int cnt[4];
    __shared__ int res;
    if (t < 4) cnt[t] = 0;
    __syncthreads();
    if (b == 1) {
        const uint8_t* m = (const uint8_t*)a.p[1];
        int c0 = 0, c1 = 0, c2 = 0, c3 = 0;
        for (int i = t; i < 4096; i += 256) {
            uint8_t v = m[i];
            int mod = i & 3;
            if (v == 0x3F && mod == 1) c0++;
            if (v == 0x3F && mod == 3) c1++;
            if (v == 1 && mod != 0) c2++;
            if (v == 1 && mod == 0) c3++;
        }
        atomicAdd(&cnt[0], c0); atomicAdd(&cnt[1], c1); atomicAdd(&cnt[2], c2); atomicAdd(&cnt[3], c3);
        __syncthreads();
        if (t == 0) {
            int mf;
            if (cnt[0] > 0) mf = 2;
            else if (cnt[1] > 0) mf = 3;
            else if (cnt[2] > 0) mf = 0;
            else if (cnt[3] > 0) mf = 1;
            else mf = 0;
            flags[1] = mf;
            res = mf;
        }
        __syncthreads();
        const int mf = res;
        for (int i = t; i < 4096; i += 256) {
            bool on;
            if (mf == 0)      on = ((const uint8_t*)a.p[1])[i]  != 0;
            else if (mf == 1) on = ((const int*)a.p[1])[i]      != 0;
            else if (mf == 2) on = ((const u16*)a.p[1])[i]      != 0;
            else              on = ((const uint32_t*)a.p[1])[i] != 0;
            maskb[i] = on ? -1e9f : 0.0f;
        }
    } else {
        const u16* p = (const u16*)a.p[b];
        int nw = a.nw[b];
        int nze = 0, pe = 0, nzo = 0;
        for (int i = t; i < nw; i += 256) {
            u16 w = p[i];
            if (w == 0) continue;
            int e = (w >> 7) & 0xFF;
            bool pl = (e >= 90 && e <= 140);
            if ((i & 1) == 0) { nze++; if (pl) pe++; }
            else nzo++;
        }
        atomicAdd(&cnt[0], nze); atomicAdd(&cnt[1], pe); atomicAdd(&cnt[2], nzo);
        __syncthreads();
        if (t == 0) {
            int f;
            if (cnt[0] > 0)      f = (cnt[1] * 10 >= cnt[0] * 6) ? 2 : 3;
            else if (cnt[2] > 0) f = 3;
            else                 f = 2;
            flags[b] = f;
            res = f;
        }
        __syncthreads();
        const int po = a.paroff[b];
        if (po >= 0) {
            const int f = res;
            const int n = a.nw[b];   // full element count for params (<=4096)
            for (int i = t; i < n; i += 256)
                par[po + i] = (f == 2) ? bf2f(((const u16*)a.p[b])[i])
                                       : ((const float*)a.p[b])[i];
        }
    }
}

__global__ __launch_bounds__(256) void k_convert_bf(const void* src, u16* dst, int n, const int* flag)
{
    int i = blockIdx.x * 256 + threadIdx.x;
    if (i >= n) return;
    if (*flag == 2) dst[i] = ((const u16*)src)[i];
    else            dst[i] = f2bf(((const float*)src)[i]);
}

// ---------------------------------------------------------------------------
// Fused LDS-tiled weight transposes
// ---------------------------------------------------------------------------
struct TransArgs { const void* src[6]; u16* dst[6]; int R[6]; int C[6]; int flagidx[6]; int tstart[7]; };

__global__ __launch_bounds__(256) void k_transpose_all(TransArgs a, const int* flags)
{
    const int tb = blockIdx.x;
    int s = 0;
    while (tb >= a.tstart[s + 1]) s++;
    const int lt = tb - a.tstart[s];
    const int R = a.R[s], C = a.C[s];
    const int tilesX = C >> 5;
    const int ti = lt / tilesX, tj = lt - ti * tilesX;
    const int r0 = ti * 32, c0 = tj * 32;
    const bool isbf = (flags[a.flagidx[s]] == 2);
    const int t = threadIdx.x;
    const int j = t & 31, i0 = t >> 5;
    __shared__ u16 tile[32][33];
#pragma unroll
    for (int p = 0; p < 4; p++) {
        int r = r0 + i0 + p * 8;
        size_t idx = (size_t)r * C + c0 + j;
        u16 v = isbf ? ((const u16*)a.src[s])[idx] : f2bf(((const float*)a.src[s])[idx]);
        tile[i0 + p * 8][j] = v;
    }
    __syncthreads();
    u16* dst = a.dst[s];
#pragma unroll
    for (int p = 0; p < 4; p++) {
        int c = i0 + p * 8;
        dst[(size_t)(c0 + c) * R + r0 + j] = tile[j][c];
    }
}

// ---------------------------------------------------------------------------
// MFMA GEMM core, BK=64, async global->LDS staging with XOR-swizzled layout.
// C(M x N) = A(M x K, lda) * Bt(N x K, ldb)^T. fp32 accum. 256 threads.
// ---------------------------------------------------------------------------
template<int BM, int BN, int WR, int WC, int TM, int TN>
DEV void gemm_tile(const u16* __restrict__ A, int lda,
                   const u16* __restrict__ Bt, int ldb, int K,
                   u16* As, u16* Bs, f32x4 (&acc)[TM][TN])
{
    const int t = threadIdx.x;
    const int lane = t & 63;
    const int wave = t >> 6;
    const int wr = wave / WC;
    const int wc = wave % WC;
    const int m16 = lane & 15;
    const int quad = lane >> 4;
    const int lr8 = lane >> 3;                 // 0..7 row within 8-row chunk
    const int lsw = (((lane & 7) ^ lr8) << 3); // swizzled col offset (elements)

#pragma unroll
    for (int i = 0; i < TM; i++)
#pragma unroll
        for (int j = 0; j < TN; j++) {
            acc[i][j][0] = 0.f; acc[i][j][1] = 0.f; acc[i][j][2] = 0.f; acc[i][j][3] = 0.f;
        }

    for (int kb = 0; kb < K; kb += 64) {
#pragma unroll
        for (int i = 0; i < BM / 32; i++) {
            int chunk = wave * (BM / 32) + i;
            int r = chunk * 8 + lr8;
            async16(A + (size_t)r * lda + kb + lsw, As + chunk * 512);
        }
#pragma unroll
        for (int i = 0; i < BN / 32; i++) {
            int chunk = wave * (BN / 32) + i;
            int r = chunk * 8 + lr8;
            async16(Bt + (size_t)r * ldb + kb + lsw, Bs + chunk * 512);
        }
        __syncthreads();   // drains vmcnt (incl. global_load_lds) before LDS reads
#pragma unroll
        for (int ks = 0; ks < 2; ks++) {
            bf16x8 af[TM], bfr[TN];
#pragma unroll
            for (int i = 0; i < TM; i++) {
                int row = wr * TM * 16 + i * 16 + m16;
                int jq = ks * 4 + quad;
                af[i] = *(const bf16x8*)(As + row * 64 + ((jq ^ (row & 7)) << 3));
            }
#pragma unroll
            for (int j = 0; j < TN; j++) {
                int row = wc * TN * 16 + j * 16 + m16;
                int jq = ks * 4 + quad;
                bfr[j] = *(const bf16x8*)(Bs + row * 64 + ((jq ^ (row & 7)) << 3));
            }
#pragma unroll
            for (int i = 0; i < TM; i++)
#pragma unroll
                for (int j = 0; j < TN; j++)
                    acc[i][j] = __builtin_amdgcn_mfma_f32_16x16x32_bf16(af[i], bfr[j], acc[i][j], 0, 0, 0);
        }
        __syncthreads();
    }
}

template<bool RELU>
__global__ __launch_bounds__(256) void k_gemm_std(const u16* __restrict__ A, int lda,
                                                  const u16* __restrict__ Bt, int ldb,
                                                  const float* __restrict__ bias,
                                                  u16* __restrict__ C, int ldc, int K)
{
    __shared__ __align__(16) u16 As[128 * 64];
    __shared__ __align__(16) u16 Bs[128 * 64];
    const u16* Ab = A + (size_t)blockIdx.y * 128 * lda;
    const u16* Bb = Bt + (size_t)blockIdx.x * 128 * ldb;
    f32x4 acc[4][4];
    gemm_tile<128, 128, 2, 2, 4, 4>(Ab, lda, Bb, ldb, K, As, Bs, acc);

    const int t = threadIdx.x, lane = t & 63, wave = t >> 6;
    const int wr = wave >> 1, wc = wave & 1, m16 = lane & 15, quad = lane >> 4;
    const size_t rowBase = (size_t)blockIdx.y * 128 + wr * 64;
    const int colBase = blockIdx.x * 128 + wc * 64;
#pragma unroll
    for (int tm = 0; tm < 4; tm++)
#pragma unroll
        for (int tn = 0; tn < 4; tn++) {
            int col = colBase + tn * 16 + m16;
            float bv = bias ? bias[col] : 0.f;
#pragma unroll
            for (int r = 0; r < 4; r++) {
                size_t row = rowBase + tm * 16 + quad * 4 + r;
                float v = acc[tm][tn][r] + bv;
                if (RELU) v = fmaxf(v, 0.f);
                C[row * (size_t)ldc + col] = f2bf(v);
            }
        }
}

// ---------------------------------------------------------------------------
// 128x64-tile GEMM (the k_gemm_ctx-proven <128,64,4,1,2,4> config) for the
// narrow-N GEMMs (merge N=1024, FFN2 grouped N=512). Doubles the grid vs
// 128^2 tiles -> ~4 blocks/CU so barrier drains hide behind co-resident
// waves. LDS 24 KB, acc 2x4 (32 AGPRs).
// C(row, colBase+0..63) = A(M x K, lda) * Bt rows [bx*64, bx*64+64).
// ---------------------------------------------------------------------------
__global__ __launch_bounds__(256) void k_gemm_mrg(const u16* __restrict__ A, int lda,
                                                  const u16* __restrict__ Bt, int ldb,
                                                  const float* __restrict__ bias,
                                                  u16* __restrict__ C, int ldc, int K)
{
    __shared__ __align__(16) u16 As[128 * 64];
    __shared__ __align__(16) u16 Bs[64 * 64];
    const u16* Ab = A + (size_t)blockIdx.y * 128 * lda;
    const u16* Bb = Bt + (size_t)blockIdx.x * 64 * ldb;
    f32x4 acc[2][4];
    gemm_tile<128, 64, 4, 1, 2, 4>(Ab, lda, Bb, ldb, K, As, Bs, acc);

    const int t = threadIdx.x, lane = t & 63, wave = t >> 6;
    const int m16 = lane & 15, quad = lane >> 4;
    const int colBase = blockIdx.x * 64;
#pragma unroll
    for (int tm = 0; tm < 2; tm++)
#pragma unroll
        for (int tn = 0; tn < 4; tn++) {
            int col = colBase + tn * 16 + m16;
            float bv = bias[col];
#pragma unroll
            for (int r = 0; r < 4; r++) {
                size_t row = (size_t)blockIdx.y * 128 + wave * 32 + tm * 16 + quad * 4 + r;
                C[row * (size_t)ldc + col] = f2bf(acc[tm][tn][r] + bv);
            }
        }
}

// Fused grouped FFN2, 128x64 tiles: grid (16, 64). x -> (g = x>>3, xn = x&7).
__global__ __launch_bounds__(256) void k_gemm_f2(const u16* __restrict__ h1,
                                                 const u16* __restrict__ W2T,
                                                 const float* __restrict__ b2,
                                                 u16* __restrict__ out)
{
    __shared__ __align__(16) u16 As[128 * 64];
    __shared__ __align__(16) u16 Bs[64 * 64];
    const int xi = blockIdx.x;
    const int g = xi >> 3, xn = xi & 7;
    const u16* Ab = h1 + (size_t)blockIdx.y * 128 * 4096 + g * 2048;
    const u16* Bb = W2T + (size_t)xn * 64 * 2048;
    f32x4 acc[2][4];
    gemm_tile<128, 64, 4, 1, 2, 4>(Ab, 4096, Bb, 2048, 2048, As, Bs, acc);

    const int t = threadIdx.x, lane = t & 63, wave = t >> 6;
    const int m16 = lane & 15, quad = lane >> 4;
    const int colg = xn * 64;
#pragma unroll
    for (int tm = 0; tm < 2; tm++)
#pragma unroll
        for (int tn = 0; tn < 4; tn++) {
            int cg = colg + tn * 16 + m16;
            float bv = b2[cg];
#pragma unroll
            for (int r = 0; r < 4; r++) {
                size_t row = (size_t)blockIdx.y * 128 + wave * 32 + tm * 16 + quad * 4 + r;
                out[row * 1024 + g * 512 + cg] = f2bf(acc[tm][tn][r] + bv);
            }
        }
}

// ---------------------------------------------------------------------------
// Mega-fused attention block: QKV projection + scores + softmax + P*V in ONE
// kernel. Grid 512, 512 threads = 8 waves. (round-8-verified v2)
// ---------------------------------------------------------------------------
__global__ __launch_bounds__(512, 2) void k_qkv_attn(const u16* __restrict__ y_c,
                                                     const u16* __restrict__ WqT,
                                                     const u16* __restrict__ WkT,
                                                     const u16* __restrict__ WvT,
                                                     const float* __restrict__ par,
                                                     const float* __restrict__ maskb,
                                                     u16* __restrict__ attedpre)
{
    __shared__ __align__(16) u16 smem[57344];   // 112 KB
    u16* Asb0 = smem;            // chunk even A (16384 u16)
    u16* Asb1 = smem + 16384;    // chunk odd  A
    u16* Wsb0 = smem + 32768;    // chunk even W: Wq|Wk|Wv (3 x 4096 u16)
    u16* Wsb1 = smem + 45056;    // chunk odd  W
    u16* Ks   = smem;            // phase2: 256x64 K   (aliases Asb0)
    u16* Vs   = smem + 16384;    // phase2: 64x256 V^T (aliases Asb1)
    u16* Pw8  = smem + 32768;    // Q-route + PV chunks: 8 x 2048 (aliases W bufs)

    // XCD group swizzle: wg%8 = XCD id, constant for the 8 hlow members of a
    // (bg,hbit) group. Bijective over [0,512).
    const int wg = blockIdx.x;
    const int grp = (wg >> 6) * 8 + (wg & 7);   // 0..63
    const int hlow = (wg >> 3) & 7;
    const int bg = grp >> 1, hbit = grp & 1;
    const int b = bg & 15, g = bg >> 4;
    const int t = threadIdx.x, lane = t & 63, wave = t >> 6;
    const int m16 = lane & 15, quad = lane >> 4;
    const int lr8 = lane >> 3;
    const int lsw = (((lane & 7) ^ lr8) << 3);

    // A rows: s-th row is y_c row b*512 + 2s + hbit, cols g*512.. -> stride 2048
    const u16* Yb = y_c + (size_t)(b * 512 + hbit) * 1024 + g * 512;

    f32x4 aq[2][4], ak[2][4], av[2][4];
#pragma unroll
    for (int i = 0; i < 2; i++)
#pragma unroll
        for (int j = 0; j < 4; j++) {
            aq[i][j][0]=0.f; aq[i][j][1]=0.f; aq[i][j][2]=0.f; aq[i][j][3]=0.f;
            ak[i][j][0]=0.f; ak[i][j][1]=0.f; ak[i][j][2]=0.f; ak[i][j][3]=0.f;
            av[i][j][0]=0.f; av[i][j][1]=0.f; av[i][j][2]=0.f; av[i][j][3]=0.f;
        }

    // stage chunk c (7 async16/wave: 4 A + 3 W) into buf[c&1]
    auto stage = [&](int c) {
        const int kb = c * 64;
        u16* As_ = (c & 1) ? Asb1 : Asb0;
        u16* Ws_ = (c & 1) ? Wsb1 : Wsb0;
#pragma unroll
        for (int i = 0; i < 4; i++) {
            int chunk = wave * 4 + i;
            int srow = chunk * 8 + lr8;
            async16(Yb + (size_t)srow * 2048 + kb + lsw, As_ + chunk * 512);
        }
        int row = wave * 8 + lr8;
        const size_t woff = (size_t)(hlow * 64 + row) * 512 + kb + lsw;
        async16(WqT + woff, Ws_ + wave * 512);
        async16(WkT + woff, Ws_ + 4096 + wave * 512);
        async16(WvT + woff, Ws_ + 8192 + wave * 512);
    };

    // ---- phase 1: projections over 8 K-chunks, dbuf + counted vmcnt ----
    stage(0);
    for (int c = 0; c < 8; ++c) {
        if (c + 1 < 8) {
            stage(c + 1);                                    // 7 newer in flight
            asm volatile("s_waitcnt vmcnt(7)" ::: "memory"); // chunk c landed
        } else {
            asm volatile("s_waitcnt vmcnt(0)" ::: "memory");
        }
        asm volatile("s_barrier" ::: "memory");
        const u16* As_ = (c & 1) ? Asb1 : Asb0;
        const u16* Ws_ = (c & 1) ? Wsb1 : Wsb0;
#pragma unroll
        for (int ks = 0; ks < 2; ks++) {
            const int jq = ks * 4 + quad;
            bf16x8 af[2];
#pragma unroll
            for (int mt = 0; mt < 2; mt++) {
                int row = wave * 32 + mt * 16 + m16;
                af[mt] = *(const bf16x8*)(As_ + row * 64 + ((jq ^ (row & 7)) << 3));
            }
#pragma unroll
            for (int tn = 0; tn < 4; tn++) {
                int rowb = tn * 16 + m16;
                int offb = rowb * 64 + ((jq ^ (rowb & 7)) << 3);
                bf16x8 wq = *(const bf16x8*)(Ws_ + offb);
                bf16x8 wk = *(const bf16x8*)(Ws_ + 4096 + offb);
                bf16x8 wv = *(const bf16x8*)(Ws_ + 8192 + offb);
#pragma unroll
                for (int mt = 0; mt < 2; mt++) {
                    aq[mt][tn] = __builtin_amdgcn_mfma_f32_16x16x32_bf16(af[mt], wq, aq[mt][tn], 0, 0, 0);
                    ak[mt][tn] = __builtin_amdgcn_mfma_f32_16x16x32_bf16(af[mt], wk, ak[mt][tn], 0, 0, 0);
                    av[mt][tn] = __builtin_amdgcn_mfma_f32_16x16x32_bf16(af[mt], wv, av[mt][tn], 0, 0, 0);
                }
            }
        }
        asm volatile("s_barrier" ::: "memory");   // buf[c&1] readers done
    }

    // ---- projection epilogues (post final barrier: all phase-1 LDS dead) ----
    float bQ[4], bK[4], bV[4];
#pragma unroll
    for (int tn = 0; tn < 4; tn++) {
        int c0 = hlow * 64 + tn * 16 + m16;
        bQ[tn] = par[c0]; bK[tn] = par[512 + c0]; bV[tn] = par[1024 + c0];
    }
    u16* Qw = Pw8 + wave * 2048;   // per-wave 32x64 routing chunk
#pragma unroll
    for (int tm = 0; tm < 2; tm++)
#pragma unroll
        for (int tn = 0; tn < 4; tn++) {
            int dh = tn * 16 + m16;
#pragma unroll
            for (int r = 0; r < 4; r++) {
                int sl = tm * 16 + quad * 4 + r;          // local s 0..31
                int s_ = wave * 32 + sl;                  // global s 0..255
                // K[s][dh] -> Ks, gemm swizzle keyed on s
                Ks[s_ * 64 + ((((dh >> 3) ^ (s_ & 7)) << 3) | (dh & 7))] = f2bf(ak[tm][tn][r] + bK[tn]);
                // V[s][dh] -> Vs[dh][s], PV slot map keyed on (s>>3, dh)
                {
                    int j = s_ >> 3;
                    int slot = (j & 24) | ((j & 7) ^ (dh & 7));
                    Vs[dh * 256 + slot * 8 + (s_ & 7)] = f2bf(av[tm][tn][r] + bV[tn]);
                }
                // Q -> per-wave chunk (C-layout -> A-layout routing)
                Qw[sl * 64 + ((((dh >> 3) ^ (sl & 7)) << 3) | (dh & 7))] = f2bf(aq[tm][tn][r] + bQ[tn]);
            }
        }
    // read Q back as A-frags (wave-private, compiler orders ds write->read)
    bf16x8 qf[2][2];
#pragma unroll
    for (int mt = 0; mt < 2; mt++)
#pragma unroll
        for (int ks = 0; ks < 2; ks++) {
            int row = mt * 16 + m16;
            int jq = ks * 4 + quad;
            qf[mt][ks] = *(const bf16x8*)(Qw + row * 64 + ((jq ^ (row & 7)) << 3));
        }
    float mb[16];
#pragma unroll
    for (int nt = 0; nt < 16; nt++) mb[nt] = maskb[b * 256 + nt * 16 + m16];

    __syncthreads();   // Ks/Vs visible to all waves

    // ---- S = Q K^T ----
    f32x4 s[2][16];
#pragma unroll
    for (int mt = 0; mt < 2; mt++)
#pragma unroll
        for (int nt = 0; nt < 16; nt++) { s[mt][nt][0]=0.f; s[mt][nt][1]=0.f; s[mt][nt][2]=0.f; s[mt][nt][3]=0.f; }
#pragma unroll
    for (int ks = 0; ks < 2; ks++) {
        int jq = ks * 4 + quad;
#pragma unroll
        for (int nt = 0; nt < 16; nt++) {
            int row = nt * 16 + m16;
            bf16x8 kf = *(const bf16x8*)(Ks + row * 64 + ((jq ^ (row & 7)) << 3));
#pragma unroll
            for (int mt = 0; mt < 2; mt++)
                s[mt][nt] = __builtin_amdgcn_mfma_f32_16x16x32_bf16(qf[mt][ks], kf, s[mt][nt], 0, 0, 0);
        }
    }

    // ---- softmax, fully in-wave ----
    float rinv[2][4];
#pragma unroll
    for (int mt = 0; mt < 2; mt++)
#pragma unroll
        for (int r = 0; r < 4; r++) {
            float mm = -3.0e38f;
#pragma unroll
            for (int nt = 0; nt < 16; nt++) {
                float v = s[mt][nt][r] * 0.125f + mb[nt];
                s[mt][nt][r] = v;
                mm = fmaxf(mm, v);
            }
            mm = fmaxf(mm, __shfl_xor(mm, 1));
            mm = fmaxf(mm, __shfl_xor(mm, 2));
            mm = fmaxf(mm, __shfl_xor(mm, 4));
            mm = fmaxf(mm, __shfl_xor(mm, 8));
            float ss = 0.f;
#pragma unroll
            for (int nt = 0; nt < 16; nt++) {
                float e = __expf(s[mt][nt][r] - mm);
                s[mt][nt][r] = e;
                ss += e;
            }
            ss += __shfl_xor(ss, 1);
            ss += __shfl_xor(ss, 2);
            ss += __shfl_xor(ss, 4);
            ss += __shfl_xor(ss, 8);
            rinv[mt][r] = 1.0f / ss;
        }

    // ---- ctx = P V : route P chunks through the per-wave LDS chunk ----
    f32x4 ctx[2][4];
#pragma unroll
    for (int mt = 0; mt < 2; mt++)
#pragma unroll
        for (int dt = 0; dt < 4; dt++) { ctx[mt][dt][0]=0.f; ctx[mt][dt][1]=0.f; ctx[mt][dt][2]=0.f; ctx[mt][dt][3]=0.f; }

#pragma unroll
    for (int kc = 0; kc < 4; kc++) {
#pragma unroll
        for (int mt = 0; mt < 2; mt++)
#pragma unroll
            for (int nl = 0; nl < 4; nl++) {
                int nt = kc * 4 + nl;
#pragma unroll
                for (int r = 0; r < 4; r++) {
                    int row = mt * 16 + quad * 4 + r;
                    int col = nl * 16 + m16;
                    int j = col >> 3, e = col & 7;
                    Qw[row * 64 + (((j ^ (row & 7)) << 3) | e)] = f2bf(s[mt][nt][r] * rinv[mt][r]);
                }
            }
#pragma unroll
        for (int ks = 0; ks < 2; ks++) {
            int jq = ks * 4 + quad;
            bf16x8 pf[2];
#pragma unroll
            for (int mt = 0; mt < 2; mt++) {
                int row = mt * 16 + m16;
                pf[mt] = *(const bf16x8*)(Qw + row * 64 + ((jq ^ (row & 7)) << 3));
            }
#pragma unroll
            for (int dt = 0; dt < 4; dt++) {
                int d = dt * 16 + m16;
                int j = kc * 8 + ks * 4 + quad;
                int slot = (j & 24) | ((j & 7) ^ (d & 7));
                bf16x8 vf = *(const bf16x8*)(Vs + d * 256 + slot * 8);
#pragma unroll
                for (int mt = 0; mt < 2; mt++)
                    ctx[mt][dt] = __builtin_amdgcn_mfma_f32_16x16x32_bf16(pf[mt], vf, ctx[mt][dt], 0, 0, 0);
            }
        }
    }

    // ---- scatter ctx into attedpre (B,L,H): l = 2s+hbit, col = g*512+hlow*64+dh ----
    const int cBase = g * 512 + hlow * 64;
#pragma unroll
    for (int mt = 0; mt < 2; mt++)
#pragma unroll
        for (int dt = 0; dt < 4; dt++) {
            int dh = dt * 16 + m16;
#pragma unroll
            for (int r = 0; r < 4; r++) {
                int sI = wave * 32 + mt * 16 + quad * 4 + r;
                int l = 2 * sI + hbit;
                attedpre[((size_t)b * 512 + l) * 1024 + cBase + dh] = f2bf(ctx[mt][dt][r]);
            }
        }
}

// out = LN(x1 + x2) * gamma + beta over D=1024; one block per row.
template<int FINAL>
__global__ __launch_bounds__(256) void k_ln(const u16* __restrict__ x1, const u16* __restrict__ x2,
                                            const float* __restrict__ gamma, const float* __restrict__ beta,
                                            void* __restrict__ outv, const int* __restrict__ yflag)
{
    const size_t row = blockIdx.x;
    const int t = threadIdx.x;
    us4 a = *(const us4*)(x1 + row * 1024 + t * 4);
    us4 b = *(const us4*)(x2 + row * 1024 + t * 4);
    float v[4]; float s = 0.f, s2 = 0.f;
#pragma unroll
    for (int i = 0; i < 4; i++) { v[i] = bf2f(a[i]) + bf2f(b[i]); s += v[i]; s2 += v[i] * v[i]; }
#pragma unroll
    for (int off = 32; off > 0; off >>= 1) { s += __shfl_xor(s, off); s2 += __shfl_xor(s2, off); }
    __shared__ float red[8];
    const int lane = t & 63, wave = t >> 6;
    if (lane == 0) { red[wave] = s; red[wave + 4] = s2; }
    __syncthreads();
    s = red[0] + red[1] + red[2] + red[3];
    s2 = red[4] + red[5] + red[6] + red[7];
    float mean = s * (1.0f / 1024.0f);
    float var = fmaxf(s2 * (1.0f / 1024.0f) - mean * mean, 0.0f);
    float rs = rsqrtf(var + 1e-6f);
    float o[4];
#pragma unroll
    for (int i = 0; i < 4; i++) {
        int c = t * 4 + i;
        o[i] = (v[i] - mean) * rs * gamma[c] + beta[c];
    }
    bool f32out = FINAL && yflag && (*yflag == 3);
    if (f32out) {
        float* out = (float*)outv;
#pragma unroll
        for (int i = 0; i < 4; i++) out[row * 1024 + t * 4 + i] = o[i];
    } else {
        u16* out = (u16*)outv;
        us4 ov;
#pragma unroll
        for (int i = 0; i < 4; i++) ov[i] = f2bf(o[i]);
        *(us4*)(out + row * 1024 + t * 4) = ov;
    }
}

// ---------------------------------------------------------------------------
extern "C" void kernel_launch(void* const* d_in, const int* in_sizes, int n_in,
                              void* d_out, int out_size, void* d_ws, size_t ws_size,
                              hipStream_t stream)
{
    (void)in_sizes; (void)n_in; (void)out_size; (void)ws_size;
    const void* y    = d_in[0];
    const void* mask = d_in[1];
    const void* Wv = d_in[2];  const void* bv = d_in[3];
    const void* Wk = d_in[4];  const void* bk = d_in[5];
    const void* Wq = d_in[6];  const void* bq = d_in[7];
    const void* Wm = d_in[8];  const void* bm = d_in[9];
    const void* W1 = d_in[10]; const void* b1 = d_in[11];
    const void* W2 = d_in[12]; const void* b2 = d_in[13];
    const void* g1 = d_in[14]; const void* be1 = d_in[15];
    const void* g2 = d_in[16]; const void* be2 = d_in[17];

    char* ws = (char*)d_ws;
    size_t off = 0;
    auto alloc = [&](size_t bytes) { void* p = ws + off; off = (off + bytes + 255) & ~(size_t)255; return p; };

    int*   flags = (int*)alloc(32 * 4);
    float* maskb = (float*)alloc(16 * 256 * 4);
    float* par   = (float*)alloc(11264 * 4);
    u16* WqT  = (u16*)alloc((size_t)262144 * 2);
    u16* WkT  = (u16*)alloc((size_t)262144 * 2);
    u16* WvT  = (u16*)alloc((size_t)262144 * 2);
    u16* WmT  = (u16*)alloc((size_t)1048576 * 2);
    u16* W1T  = (u16*)alloc((size_t)4194304 * 2);
    u16* W2T  = (u16*)alloc((size_t)1048576 * 2);
    u16* y_c  = (u16*)alloc((size_t)8388608 * 2);
    u16* slotA = (u16*)alloc((size_t)8388608 * 2);   // mergeout
    u16* slotB = (u16*)alloc((size_t)8388608 * 2);   // y1
    u16* slotC = (u16*)alloc((size_t)8388608 * 2);   // ffout
    u16* slotD = (u16*)alloc((size_t)8388608 * 2);   // attedpre
    u16* Pbig  = (u16*)alloc((size_t)33554432 * 2);  // h1 (64 MB region)

    float* p_bm  = par + 1536;
    float* p_b1  = par + 2560;
    float* p_b2  = par + 6656;
    float* p_g1  = par + 7168;
    float* p_be1 = par + 8192;
    float* p_g2  = par + 9216;
    float* p_be2 = par + 10240;

    DetectArgs da;
    {
        const void* srcs[18] = {y, mask, Wv, bv, Wk, bk, Wq, bq, Wm, bm, W1, b1, W2, b2, g1, be1, g2, be2};
        const int   nele[18] = {8388608, 4096, 262144, 512, 262144, 512, 262144, 512, 1048576, 1024,
                                4194304, 4096, 1048576, 512, 1024, 1024, 1024, 1024};
        // par offsets for the 10 param tensors (-1 = not a param)
        int po[18]; for (int i = 0; i < 18; i++) po[i] = -1;
        po[7]  = 0;     // bq
        po[5]  = 512;   // bk
        po[3]  = 1024;  // bv
        po[9]  = 1536;  // bm
        po[11] = 2560;  // b1
        po[13] = 6656;  // b2
        po[14] = 7168;  // g1
        po[15] = 8192;  // be1
        po[16] = 9216;  // g2
        po[17] = 10240; // be2
        for (int i = 0; i < 18; i++) {
            da.p[i] = srcs[i];
            da.nw[i] = nele[i] < 4096 ? nele[i] : 4096;
            da.paroff[i] = po[i];
        }
    }
    k_detect_all<<<18, 256, 0, stream>>>(da, flags, maskb, par);

    k_convert_bf<<<32768, 256, 0, stream>>>(y, y_c, 8388608, flags + 0);

    TransArgs ta;
    {
        const void* s6[6] = {Wq, Wk, Wv, Wm, W1, W2};
        u16* d6[6] = {WqT, WkT, WvT, WmT, W1T, W2T};
        int R6[6] = {512, 512, 512, 1024, 1024, 2048};
        int C6[6] = {512, 512, 512, 1024, 4096, 512};
        int f6[6] = {6, 4, 2, 8, 10, 12};
        int ts[7] = {0, 256, 512, 768, 1792, 5888, 6912};
        for (int i = 0; i < 6; i++) { ta.src[i] = s6[i]; ta.dst[i] = d6[i]; ta.R[i] = R6[i]; ta.C[i] = C6[i]; ta.flagidx[i] = f6[i]; }
        for (int i = 0; i < 7; i++) ta.tstart[i] = ts[i];
    }
    k_transpose_all<<<6912, 256, 0, stream>>>(ta, flags);

    u16* attedpre = slotD;
    k_qkv_attn<<<512, 512, 0, stream>>>(y_c, WqT, WkT, WvT, par, maskb, attedpre);

    u16* mergeout = slotA;
    k_gemm_mrg<<<dim3(16, 64), 256, 0, stream>>>(attedpre, 1024, WmT, 1024, p_bm, mergeout, 1024, 1024);

    u16* y1 = slotB;
    k_ln<0><<<8192, 256, 0, stream>>>(y_c, mergeout, p_g1, p_be1, y1, nullptr);

    u16* h1 = Pbig;
    k_gemm_std<true><<<dim3(32, 64), 256, 0, stream>>>(y1, 1024, W1T, 1024, p_b1, h1, 4096, 1024);

    u16* ffout = slotC;
    k_gemm_f2<<<dim3(16, 64), 256, 0, stream>>>(h1, W2T, p_b2, ffout);

    k_ln<1><<<8192, 256, 0, stream>>>(y1, ffout, p_g2, p_be2, d_out, flags + 0);
}

// Round 10
// 407.546 us; speedup vs baseline: 1.0645x; 1.0645x over previous
//
#include <hip/hip_runtime.h>
#include <stdint.h>

typedef unsigned short u16;
using us8   = __attribute__((ext_vector_type(8))) unsigned short;
using us4   = __attribute__((ext_vector_type(4))) unsigned short;
using bf16x8 = __attribute__((ext_vector_type(8))) __bf16;
using f32x4 = __attribute__((ext_vector_type(4))) float;

#define DEV static __device__ __forceinline__

DEV float bf2f(u16 u) { union { uint32_t i; float f; } v; v.i = (uint32_t)u << 16; return v.f; }
DEV u16 f2bf(float f) {
    union { float f; uint32_t i; } v; v.f = f;
    uint32_t u = v.i;
    return (u16)((u + 0x7FFFu + ((u >> 16) & 1u)) >> 16);
}

// async global->LDS 16B copy: lane l writes LDS at (uniform base) + l*16B.
DEV void async16(const u16* g, u16* ldsbase)
{
    __builtin_amdgcn_global_load_lds((const __attribute__((address_space(1))) void*)g,
                                     (__attribute__((address_space(3))) void*)ldsbase, 16, 0, 0);
}

// ---------------------------------------------------------------------------
// Fused dtype detection + mask expansion + param conversion: 18 blocks.
// (round-9 form; kept — isolated variable this round)
// ---------------------------------------------------------------------------
struct DetectArgs { const void* p[18]; int nw[18]; int paroff[18]; };

__global__ __launch_bounds__(256) void k_detect_all(DetectArgs a, int* flags,
                                                    float* maskb, float* par)
{
    const int b = blockIdx.x;
    const int t = threadIdx.x;
    __shared__ int cnt[4];
    __shared__ int res;
    if (t < 4) cnt[t] = 0;
    __syncthreads();
    if (b == 1) {
        const uint8_t* m = (const uint8_t*)a.p[1];
        int c0 = 0, c1 = 0, c2 = 0, c3 = 0;
        for (int i = t; i < 4096; i += 256) {
            uint8_t v = m[i];
            int mod = i & 3;
            if (v == 0x3F && mod == 1) c0++;
            if (v == 0x3F && mod == 3) c1++;
            if (v == 1 && mod != 0) c2++;
            if (v == 1 && mod == 0) c3++;
        }
        atomicAdd(&cnt[0], c0); atomicAdd(&cnt[1], c1); atomicAdd(&cnt[2], c2); atomicAdd(&cnt[3], c3);
        __syncthreads();
        if (t == 0) {
            int mf;
            if (cnt[0] > 0) mf = 2;
            else if (cnt[1] > 0) mf = 3;
            else if (cnt[2] > 0) mf = 0;
            else if (cnt[3] > 0) mf = 1;
            else mf = 0;
            flags[1] = mf;
            res = mf;
        }
        __syncthreads();
        const int mf = res;
        for (int i = t; i < 4096; i += 256) {
            bool on;
            if (mf == 0)      on = ((const uint8_t*)a.p[1])[i]  != 0;
            else if (mf == 1) on = ((const int*)a.p[1])[i]      != 0;
            else if (mf == 2) on = ((const u16*)a.p[1])[i]      != 0;
            else              on = ((const uint32_t*)a.p[1])[i] != 0;
            maskb[i] = on ? -1e9f : 0.0f;
        }
    } else {
        const u16* p = (const u16*)a.p[b];
        int nw = a.nw[b];
        int nze = 0, pe = 0, nzo = 0;
        for (int i = t; i < nw; i += 256) {
            u16 w = p[i];
            if (w == 0) continue;
            int e = (w >> 7) & 0xFF;
            bool pl = (e >= 90 && e <= 140);
            if ((i & 1) == 0) { nze++; if (pl) pe++; }
            else nzo++;
        }
        atomicAdd(&cnt[0], nze); atomicAdd(&cnt[1], pe); atomicAdd(&cnt[2], nzo);
        __syncthreads();
        if (t == 0) {
            int f;
            if (cnt[0] > 0)      f = (cnt[1] * 10 >= cnt[0] * 6) ? 2 : 3;
            else if (cnt[2] > 0) f = 3;
            else                 f = 2;
            flags[b] = f;
            res = f;
        }
        __syncthreads();
        const int po = a.paroff[b];
        if (po >= 0) {
            const int f = res;
            const int n = a.nw[b];   // full element count for params (<=4096)
            for (int i = t; i < n; i += 256)
                par[po + i] = (f == 2) ? bf2f(((const u16*)a.p[b])[i])
                                       : ((const float*)a.p[b])[i];
        }
    }
}

// ---------------------------------------------------------------------------
// Fused preprocessing: weight transposes (blocks 0..6911, round-8-proven
// path verbatim) + y -> bf16 conversion (blocks 6912.., k_convert_bf path
// verbatim). One launch instead of two.
// ---------------------------------------------------------------------------
struct TransArgs { const void* src[6]; u16* dst[6]; int R[6]; int C[6]; int flagidx[6]; int tstart[7]; };

__global__ __launch_bounds__(256) void k_preproc(TransArgs a, const int* flags,
                                                 const void* y, u16* y_c)
{
    __shared__ u16 tile[32][33];
    const int tb = blockIdx.x;
    const int t = threadIdx.x;
    if (tb >= 6912) {
        int i = (tb - 6912) * 256 + t;
        if (i < 8388608) {
            if (flags[0] == 2) y_c[i] = ((const u16*)y)[i];
            else               y_c[i] = f2bf(((const float*)y)[i]);
        }
        return;
    }
    int s = 0;
    while (tb >= a.tstart[s + 1]) s++;
    const int lt = tb - a.tstart[s];
    const int R = a.R[s], C = a.C[s];
    const int tilesX = C >> 5;
    const int ti = lt / tilesX, tj = lt - ti * tilesX;
    const int r0 = ti * 32, c0 = tj * 32;
    const bool isbf = (flags[a.flagidx[s]] == 2);
    const int j = t & 31, i0 = t >> 5;
#pragma unroll
    for (int p = 0; p < 4; p++) {
        int r = r0 + i0 + p * 8;
        size_t idx = (size_t)r * C + c0 + j;
        u16 v = isbf ? ((const u16*)a.src[s])[idx] : f2bf(((const float*)a.src[s])[idx]);
        tile[i0 + p * 8][j] = v;
    }
    __syncthreads();
    u16* dst = a.dst[s];
#pragma unroll
    for (int p = 0; p < 4; p++) {
        int c = i0 + p * 8;
        dst[(size_t)(c0 + c) * R + r0 + j] = tile[j][c];
    }
}

// ---------------------------------------------------------------------------
// MFMA GEMM core, BK=64, async global->LDS staging with XOR-swizzled layout.
// C(M x N) = A(M x K, lda) * Bt(N x K, ldb)^T. fp32 accum. 256 threads.
// ---------------------------------------------------------------------------
template<int BM, int BN, int WR, int WC, int TM, int TN>
DEV void gemm_tile(const u16* __restrict__ A, int lda,
                   const u16* __restrict__ Bt, int ldb, int K,
                   u16* As, u16* Bs, f32x4 (&acc)[TM][TN])
{
    const int t = threadIdx.x;
    const int lane = t & 63;
    const int wave = t >> 6;
    const int wr = wave / WC;
    const int wc = wave % WC;
    const int m16 = lane & 15;
    const int quad = lane >> 4;
    const int lr8 = lane >> 3;                 // 0..7 row within 8-row chunk
    const int lsw = (((lane & 7) ^ lr8) << 3); // swizzled col offset (elements)

#pragma unroll
    for (int i = 0; i < TM; i++)
#pragma unroll
        for (int j = 0; j < TN; j++) {
            acc[i][j][0] = 0.f; acc[i][j][1] = 0.f; acc[i][j][2] = 0.f; acc[i][j][3] = 0.f;
        }

    for (int kb = 0; kb < K; kb += 64) {
#pragma unroll
        for (int i = 0; i < BM / 32; i++) {
            int chunk = wave * (BM / 32) + i;
            int r = chunk * 8 + lr8;
            async16(A + (size_t)r * lda + kb + lsw, As + chunk * 512);
        }
#pragma unroll
        for (int i = 0; i < BN / 32; i++) {
            int chunk = wave * (BN / 32) + i;
            int r = chunk * 8 + lr8;
            async16(Bt + (size_t)r * ldb + kb + lsw, Bs + chunk * 512);
        }
        __syncthreads();   // drains vmcnt (incl. global_load_lds) before LDS reads
#pragma unroll
        for (int ks = 0; ks < 2; ks++) {
            bf16x8 af[TM], bfr[TN];
#pragma unroll
            for (int i = 0; i < TM; i++) {
                int row = wr * TM * 16 + i * 16 + m16;
                int jq = ks * 4 + quad;
                af[i] = *(const bf16x8*)(As + row * 64 + ((jq ^ (row & 7)) << 3));
            }
#pragma unroll
            for (int j = 0; j < TN; j++) {
                int row = wc * TN * 16 + j * 16 + m16;
                int jq = ks * 4 + quad;
                bfr[j] = *(const bf16x8*)(Bs + row * 64 + ((jq ^ (row & 7)) << 3));
            }
#pragma unroll
            for (int i = 0; i < TM; i++)
#pragma unroll
                for (int j = 0; j < TN; j++)
                    acc[i][j] = __builtin_amdgcn_mfma_f32_16x16x32_bf16(af[i], bfr[j], acc[i][j], 0, 0, 0);
        }
        __syncthreads();
    }
}

template<bool RELU>
__global__ __launch_bounds__(256) void k_gemm_std(const u16* __restrict__ A, int lda,
                                                  const u16* __restrict__ Bt, int ldb,
                                                  const float* __restrict__ bias,
                                                  u16* __restrict__ C, int ldc, int K)
{
    __shared__ __align__(16) u16 As[128 * 64];
    __shared__ __align__(16) u16 Bs[128 * 64];
    const u16* Ab = A + (size_t)blockIdx.y * 128 * lda;
    const u16* Bb = Bt + (size_t)blockIdx.x * 128 * ldb;
    f32x4 acc[4][4];
    gemm_tile<128, 128, 2, 2, 4, 4>(Ab, lda, Bb, ldb, K, As, Bs, acc);

    const int t = threadIdx.x, lane = t & 63, wave = t >> 6;
    const int wr = wave >> 1, wc = wave & 1, m16 = lane & 15, quad = lane >> 4;
    const size_t rowBase = (size_t)blockIdx.y * 128 + wr * 64;
    const int colBase = blockIdx.x * 128 + wc * 64;
#pragma unroll
    for (int tm = 0; tm < 4; tm++)
#pragma unroll
        for (int tn = 0; tn < 4; tn++) {
            int col = colBase + tn * 16 + m16;
            float bv = bias ? bias[col] : 0.f;
#pragma unroll
            for (int r = 0; r < 4; r++) {
                size_t row = rowBase + tm * 16 + quad * 4 + r;
                float v = acc[tm][tn][r] + bv;
                if (RELU) v = fmaxf(v, 0.f);
                C[row * (size_t)ldc + col] = f2bf(v);
            }
        }
}

// Fused grouped FFN2: grid (8, 64). x -> (g = x>>2, xn = x&3). (round-8 form)
__global__ __launch_bounds__(256) void k_gemm_ffn2(const u16* __restrict__ h1,
                                                   const u16* __restrict__ W2T,
                                                   const float* __restrict__ b2,
                                                   u16* __restrict__ out)
{
    __shared__ __align__(16) u16 As[128 * 64];
    __shared__ __align__(16) u16 Bs[128 * 64];
    const int xi = blockIdx.x;
    const int g = xi >> 2, xn = xi & 3;
    const u16* Ab = h1 + (size_t)blockIdx.y * 128 * 4096 + g * 2048;
    const u16* Bb = W2T + (size_t)xn * 128 * 2048;
    f32x4 acc[4][4];
    gemm_tile<128, 128, 2, 2, 4, 4>(Ab, 4096, Bb, 2048, 2048, As, Bs, acc);

    const int t = threadIdx.x, lane = t & 63, wave = t >> 6;
    const int wr = wave >> 1, wc = wave & 1, m16 = lane & 15, quad = lane >> 4;
    const size_t rowBase = (size_t)blockIdx.y * 128 + wr * 64;
    const int colg = xn * 128 + wc * 64;
#pragma unroll
    for (int tm = 0; tm < 4; tm++)
#pragma unroll
        for (int tn = 0; tn < 4; tn++) {
            int cg = colg + tn * 16 + m16;
            float bv = b2[cg];
#pragma unroll
            for (int r = 0; r < 4; r++) {
                size_t row = rowBase + tm * 16 + quad * 4 + r;
                out[row * 1024 + g * 512 + cg] = f2bf(acc[tm][tn][r] + bv);
            }
        }
}

// ---------------------------------------------------------------------------
// Mega-fused attention block: QKV projection + scores + softmax + P*V in ONE
// kernel. Grid 512, 512 threads = 8 waves. (round-8-verified v2)
// ---------------------------------------------------------------------------
__global__ __launch_bounds__(512, 2) void k_qkv_attn(const u16* __restrict__ y_c,
                                                     const u16* __restrict__ WqT,
                                                     const u16* __restrict__ WkT,
                                                     const u16* __restrict__ WvT,
                                                     const float* __restrict__ par,
                                                     const float* __restrict__ maskb,
                                                     u16* __restrict__ attedpre)
{
    __shared__ __align__(16) u16 smem[57344];   // 112 KB
    u16* Asb0 = smem;            // chunk even A (16384 u16)
    u16* Asb1 = smem + 16384;    // chunk odd  A
    u16* Wsb0 = smem + 32768;    // chunk even W: Wq|Wk|Wv (3 x 4096 u16)
    u16* Wsb1 = smem + 45056;    // chunk odd  W
    u16* Ks   = smem;            // phase2: 256x64 K   (aliases Asb0)
    u16* Vs   = smem + 16384;    // phase2: 64x256 V^T (aliases Asb1)
    u16* Pw8  = smem + 32768;    // Q-route + PV chunks: 8 x 2048 (aliases W bufs)

    // XCD group swizzle: wg%8 = XCD id, constant for the 8 hlow members of a
    // (bg,hbit) group. Bijective over [0,512).
    const int wg = blockIdx.x;
    const int grp = (wg >> 6) * 8 + (wg & 7);   // 0..63
    const int hlow = (wg >> 3) & 7;
    const int bg = grp >> 1, hbit = grp & 1;
    const int b = bg & 15, g = bg >> 4;
    const int t = threadIdx.x, lane = t & 63, wave = t >> 6;
    const int m16 = lane & 15, quad = lane >> 4;
    const int lr8 = lane >> 3;
    const int lsw = (((lane & 7) ^ lr8) << 3);

    // A rows: s-th row is y_c row b*512 + 2s + hbit, cols g*512.. -> stride 2048
    const u16* Yb = y_c + (size_t)(b * 512 + hbit) * 1024 + g * 512;

    f32x4 aq[2][4], ak[2][4], av[2][4];
#pragma unroll
    for (int i = 0; i < 2; i++)
#pragma unroll
        for (int j = 0; j < 4; j++) {
            aq[i][j][0]=0.f; aq[i][j][1]=0.f; aq[i][j][2]=0.f; aq[i][j][3]=0.f;
            ak[i][j][0]=0.f; ak[i][j][1]=0.f; ak[i][j][2]=0.f; ak[i][j][3]=0.f;
            av[i][j][0]=0.f; av[i][j][1]=0.f; av[i][j][2]=0.f; av[i][j][3]=0.f;
        }

    // stage chunk c (7 async16/wave: 4 A + 3 W) into buf[c&1]
    auto stage = [&](int c) {
        const int kb = c * 64;
        u16* As_ = (c & 1) ? Asb1 : Asb0;
        u16* Ws_ = (c & 1) ? Wsb1 : Wsb0;
#pragma unroll
        for (int i = 0; i < 4; i++) {
            int chunk = wave * 4 + i;
            int srow = chunk * 8 + lr8;
            async16(Yb + (size_t)srow * 2048 + kb + lsw, As_ + chunk * 512);
        }
        int row = wave * 8 + lr8;
        const size_t woff = (size_t)(hlow * 64 + row) * 512 + kb + lsw;
        async16(WqT + woff, Ws_ + wave * 512);
        async16(WkT + woff, Ws_ + 4096 + wave * 512);
        async16(WvT + woff, Ws_ + 8192 + wave * 512);
    };

    // ---- phase 1: projections over 8 K-chunks, dbuf + counted vmcnt ----
    stage(0);
    for (int c = 0; c < 8; ++c) {
        if (c + 1 < 8) {
            stage(c + 1);                                    // 7 newer in flight
            asm volatile("s_waitcnt vmcnt(7)" ::: "memory"); // chunk c landed
        } else {
            asm volatile("s_waitcnt vmcnt(0)" ::: "memory");
        }
        asm volatile("s_barrier" ::: "memory");
        const u16* As_ = (c & 1) ? Asb1 : Asb0;
        const u16* Ws_ = (c & 1) ? Wsb1 : Wsb0;
#pragma unroll
        for (int ks = 0; ks < 2; ks++) {
            const int jq = ks * 4 + quad;
            bf16x8 af[2];
#pragma unroll
            for (int mt = 0; mt < 2; mt++) {
                int row = wave * 32 + mt * 16 + m16;
                af[mt] = *(const bf16x8*)(As_ + row * 64 + ((jq ^ (row & 7)) << 3));
            }
#pragma unroll
            for (int tn = 0; tn < 4; tn++) {
                int rowb = tn * 16 + m16;
                int offb = rowb * 64 + ((jq ^ (rowb & 7)) << 3);
                bf16x8 wq = *(const bf16x8*)(Ws_ + offb);
                bf16x8 wk = *(const bf16x8*)(Ws_ + 4096 + offb);
                bf16x8 wv = *(const bf16x8*)(Ws_ + 8192 + offb);
#pragma unroll
                for (int mt = 0; mt < 2; mt++) {
                    aq[mt][tn] = __builtin_amdgcn_mfma_f32_16x16x32_bf16(af[mt], wq, aq[mt][tn], 0, 0, 0);
                    ak[mt][tn] = __builtin_amdgcn_mfma_f32_16x16x32_bf16(af[mt], wk, ak[mt][tn], 0, 0, 0);
                    av[mt][tn] = __builtin_amdgcn_mfma_f32_16x16x32_bf16(af[mt], wv, av[mt][tn], 0, 0, 0);
                }
            }
        }
        asm volatile("s_barrier" ::: "memory");   // buf[c&1] readers done
    }

    // ---- projection epilogues (post final barrier: all phase-1 LDS dead) ----
    float bQ[4], bK[4], bV[4];
#pragma unroll
    for (int tn = 0; tn < 4; tn++) {
        int c0 = hlow * 64 + tn * 16 + m16;
        bQ[tn] = par[c0]; bK[tn] = par[512 + c0]; bV[tn] = par[1024 + c0];
    }
    u16* Qw = Pw8 + wave * 2048;   // per-wave 32x64 routing chunk
#pragma unroll
    for (int tm = 0; tm < 2; tm++)
#pragma unroll
        for (int tn = 0; tn < 4; tn++) {
            int dh = tn * 16 + m16;
#pragma unroll
            for (int r = 0; r < 4; r++) {
                int sl = tm * 16 + quad * 4 + r;          // local s 0..31
                int s_ = wave * 32 + sl;                  // global s 0..255
                // K[s][dh] -> Ks, gemm swizzle keyed on s
                Ks[s_ * 64 + ((((dh >> 3) ^ (s_ & 7)) << 3) | (dh & 7))] = f2bf(ak[tm][tn][r] + bK[tn]);
                // V[s][dh] -> Vs[dh][s], PV slot map keyed on (s>>3, dh)
                {
                    int j = s_ >> 3;
                    int slot = (j & 24) | ((j & 7) ^ (dh & 7));
                    Vs[dh * 256 + slot * 8 + (s_ & 7)] = f2bf(av[tm][tn][r] + bV[tn]);
                }
                // Q -> per-wave chunk (C-layout -> A-layout routing)
                Qw[sl * 64 + ((((dh >> 3) ^ (sl & 7)) << 3) | (dh & 7))] = f2bf(aq[tm][tn][r] + bQ[tn]);
            }
        }
    // read Q back as A-frags (wave-private, compiler orders ds write->read)
    bf16x8 qf[2][2];
#pragma unroll
    for (int mt = 0; mt < 2; mt++)
#pragma unroll
        for (int ks = 0; ks < 2; ks++) {
            int row = mt * 16 + m16;
            int jq = ks * 4 + quad;
            qf[mt][ks] = *(const bf16x8*)(Qw + row * 64 + ((jq ^ (row & 7)) << 3));
        }
    float mb[16];
#pragma unroll
    for (int nt = 0; nt < 16; nt++) mb[nt] = maskb[b * 256 + nt * 16 + m16];

    __syncthreads();   // Ks/Vs visible to all waves

    // ---- S = Q K^T ----
    f32x4 s[2][16];
#pragma unroll
    for (int mt = 0; mt < 2; mt++)
#pragma unroll
        for (int nt = 0; nt < 16; nt++) { s[mt][nt][0]=0.f; s[mt][nt][1]=0.f; s[mt][nt][2]=0.f; s[mt][nt][3]=0.f; }
#pragma unroll
    for (int ks = 0; ks < 2; ks++) {
        int jq = ks * 4 + quad;
#pragma unroll
        for (int nt = 0; nt < 16; nt++) {
            int row = nt * 16 + m16;
            bf16x8 kf = *(const bf16x8*)(Ks + row * 64 + ((jq ^ (row & 7)) << 3));
#pragma unroll
            for (int mt = 0; mt < 2; mt++)
                s[mt][nt] = __builtin_amdgcn_mfma_f32_16x16x32_bf16(qf[mt][ks], kf, s[mt][nt], 0, 0, 0);
        }
    }

    // ---- softmax, fully in-wave ----
    float rinv[2][4];
#pragma unroll
    for (int mt = 0; mt < 2; mt++)
#pragma unroll
        for (int r = 0; r < 4; r++) {
            float mm = -3.0e38f;
#pragma unroll
            for (int nt = 0; nt < 16; nt++) {
                float v = s[mt][nt][r] * 0.125f + mb[nt];
                s[mt][nt][r] = v;
                mm = fmaxf(mm, v);
            }
            mm = fmaxf(mm, __shfl_xor(mm, 1));
            mm = fmaxf(mm, __shfl_xor(mm, 2));
            mm = fmaxf(mm, __shfl_xor(mm, 4));
            mm = fmaxf(mm, __shfl_xor(mm, 8));
            float ss = 0.f;
#pragma unroll
            for (int nt = 0; nt < 16; nt++) {
                float e = __expf(s[mt][nt][r] - mm);
                s[mt][nt][r] = e;
                ss += e;
            }
            ss += __shfl_xor(ss, 1);
            ss += __shfl_xor(ss, 2);
            ss += __shfl_xor(ss, 4);
            ss += __shfl_xor(ss, 8);
            rinv[mt][r] = 1.0f / ss;
        }

    // ---- ctx = P V : route P chunks through the per-wave LDS chunk ----
    f32x4 ctx[2][4];
#pragma unroll
    for (int mt = 0; mt < 2; mt++)
#pragma unroll
        for (int dt = 0; dt < 4; dt++) { ctx[mt][dt][0]=0.f; ctx[mt][dt][1]=0.f; ctx[mt][dt][2]=0.f; ctx[mt][dt][3]=0.f; }

#pragma unroll
    for (int kc = 0; kc < 4; kc++) {
#pragma unroll
        for (int mt = 0; mt < 2; mt++)
#pragma unroll
            for (int nl = 0; nl < 4; nl++) {
                int nt = kc * 4 + nl;
#pragma unroll
                for (int r = 0; r < 4; r++) {
                    int row = mt * 16 + quad * 4 + r;
                    int col = nl * 16 + m16;
                    int j = col >> 3, e = col & 7;
                    Qw[row * 64 + (((j ^ (row & 7)) << 3) | e)] = f2bf(s[mt][nt][r] * rinv[mt][r]);
                }
            }
#pragma unroll
        for (int ks = 0; ks < 2; ks++) {
            int jq = ks * 4 + quad;
            bf16x8 pf[2];
#pragma unroll
            for (int mt = 0; mt < 2; mt++) {
                int row = mt * 16 + m16;
                pf[mt] = *(const bf16x8*)(Qw + row * 64 + ((jq ^ (row & 7)) << 3));
            }
#pragma unroll
            for (int dt = 0; dt < 4; dt++) {
                int d = dt * 16 + m16;
                int j = kc * 8 + ks * 4 + quad;
                int slot = (j & 24) | ((j & 7) ^ (d & 7));
                bf16x8 vf = *(const bf16x8*)(Vs + d * 256 + slot * 8);
#pragma unroll
                for (int mt = 0; mt < 2; mt++)
                    ctx[mt][dt] = __builtin_amdgcn_mfma_f32_16x16x32_bf16(pf[mt], vf, ctx[mt][dt], 0, 0, 0);
            }
        }
    }

    // ---- scatter ctx into attedpre (B,L,H): l = 2s+hbit, col = g*512+hlow*64+dh ----
    const int cBase = g * 512 + hlow * 64;
#pragma unroll
    for (int mt = 0; mt < 2; mt++)
#pragma unroll
        for (int dt = 0; dt < 4; dt++) {
            int dh = dt * 16 + m16;
#pragma unroll
            for (int r = 0; r < 4; r++) {
                int sI = wave * 32 + mt * 16 + quad * 4 + r;
                int l = 2 * sI + hbit;
                attedpre[((size_t)b * 512 + l) * 1024 + cBase + dh] = f2bf(ctx[mt][dt][r]);
            }
        }
}

// out = LN(x1 + x2) * gamma + beta over D=1024; one block per row.
template<int FINAL>
__global__ __launch_bounds__(256) void k_ln(const u16* __restrict__ x1, const u16* __restrict__ x2,
                                            const float* __restrict__ gamma, const float* __restrict__ beta,
                                            void* __restrict__ outv, const int* __restrict__ yflag)
{
    const size_t row = blockIdx.x;
    const int t = threadIdx.x;
    us4 a = *(const us4*)(x1 + row * 1024 + t * 4);
    us4 b = *(const us4*)(x2 + row * 1024 + t * 4);
    float v[4]; float s = 0.f, s2 = 0.f;
#pragma unroll
    for (int i = 0; i < 4; i++) { v[i] = bf2f(a[i]) + bf2f(b[i]); s += v[i]; s2 += v[i] * v[i]; }
#pragma unroll
    for (int off = 32; off > 0; off >>= 1) { s += __shfl_xor(s, off); s2 += __shfl_xor(s2, off); }
    __shared__ float red[8];
    const int lane = t & 63, wave = t >> 6;
    if (lane == 0) { red[wave] = s; red[wave + 4] = s2; }
    __syncthreads();
    s = red[0] + red[1] + red[2] + red[3];
    s2 = red[4] + red[5] + red[6] + red[7];
    float mean = s * (1.0f / 1024.0f);
    float var = fmaxf(s2 * (1.0f / 1024.0f) - mean * mean, 0.0f);
    float rs = rsqrtf(var + 1e-6f);
    float o[4];
#pragma unroll
    for (int i = 0; i < 4; i++) {
        int c = t * 4 + i;
        o[i] = (v[i] - mean) * rs * gamma[c] + beta[c];
    }
    bool f32out = FINAL && yflag && (*yflag == 3);
    if (f32out) {
        float* out = (float*)outv;
#pragma unroll
        for (int i = 0; i < 4; i++) out[row * 1024 + t * 4 + i] = o[i];
    } else {
        u16* out = (u16*)outv;
        us4 ov;
#pragma unroll
        for (int i = 0; i < 4; i++) ov[i] = f2bf(o[i]);
        *(us4*)(out + row * 1024 + t * 4) = ov;
    }
}

// ---------------------------------------------------------------------------
extern "C" void kernel_launch(void* const* d_in, const int* in_sizes, int n_in,
                              void* d_out, int out_size, void* d_ws, size_t ws_size,
                              hipStream_t stream)
{
    (void)in_sizes; (void)n_in; (void)out_size; (void)ws_size;
    const void* y    = d_in[0];
    const void* mask = d_in[1];
    const void* Wv = d_in[2];  const void* bv = d_in[3];
    const void* Wk = d_in[4];  const void* bk = d_in[5];
    const void* Wq = d_in[6];  const void* bq = d_in[7];
    const void* Wm = d_in[8];  const void* bm = d_in[9];
    const void* W1 = d_in[10]; const void* b1 = d_in[11];
    const void* W2 = d_in[12]; const void* b2 = d_in[13];
    const void* g1 = d_in[14]; const void* be1 = d_in[15];
    const void* g2 = d_in[16]; const void* be2 = d_in[17];

    char* ws = (char*)d_ws;
    size_t off = 0;
    auto alloc = [&](size_t bytes) { void* p = ws + off; off = (off + bytes + 255) & ~(size_t)255; return p; };

    int*   flags = (int*)alloc(32 * 4);
    float* maskb = (float*)alloc(16 * 256 * 4);
    float* par   = (float*)alloc(11264 * 4);
    u16* WqT  = (u16*)alloc((size_t)262144 * 2);
    u16* WkT  = (u16*)alloc((size_t)262144 * 2);
    u16* WvT  = (u16*)alloc((size_t)262144 * 2);
    u16* WmT  = (u16*)alloc((size_t)1048576 * 2);
    u16* W1T  = (u16*)alloc((size_t)4194304 * 2);
    u16* W2T  = (u16*)alloc((size_t)1048576 * 2);
    u16* y_c  = (u16*)alloc((size_t)8388608 * 2);
    u16* slotA = (u16*)alloc((size_t)8388608 * 2);   // mergeout
    u16* slotB = (u16*)alloc((size_t)8388608 * 2);   // y1
    u16* slotC = (u16*)alloc((size_t)8388608 * 2);   // ffout
    u16* slotD = (u16*)alloc((size_t)8388608 * 2);   // attedpre
    u16* Pbig  = (u16*)alloc((size_t)33554432 * 2);  // h1 (64 MB region)

    float* p_bm  = par + 1536;
    float* p_b1  = par + 2560;
    float* p_b2  = par + 6656;
    float* p_g1  = par + 7168;
    float* p_be1 = par + 8192;
    float* p_g2  = par + 9216;
    float* p_be2 = par + 10240;

    DetectArgs da;
    {
        const void* srcs[18] = {y, mask, Wv, bv, Wk, bk, Wq, bq, Wm, bm, W1, b1, W2, b2, g1, be1, g2, be2};
        const int   nele[18] = {8388608, 4096, 262144, 512, 262144, 512, 262144, 512, 1048576, 1024,
                                4194304, 4096, 1048576, 512, 1024, 1024, 1024, 1024};
        // par offsets for the 10 param tensors (-1 = not a param)
        int po[18]; for (int i = 0; i < 18; i++) po[i] = -1;
        po[7]  = 0;     // bq
        po[5]  = 512;   // bk
        po[3]  = 1024;  // bv
        po[9]  = 1536;  // bm
        po[11] = 2560;  // b1
        po[13] = 6656;  // b2
        po[14] = 7168;  // g1
        po[15] = 8192;  // be1
        po[16] = 9216;  // g2
        po[17] = 10240; // be2
        for (int i = 0; i < 18; i++) {
            da.p[i] = srcs[i];
            da.nw[i] = nele[i] < 4096 ? nele[i] : 4096;
            da.paroff[i] = po[i];
        }
    }
    k_detect_all<<<18, 256, 0, stream>>>(da, flags, maskb, par);

    TransArgs ta;
    {
        const void* s6[6] = {Wq, Wk, Wv, Wm, W1, W2};
        u16* d6[6] = {WqT, WkT, WvT, WmT, W1T, W2T};
        int R6[6] = {512, 512, 512, 1024, 1024, 2048};
        int C6[6] = {512, 512, 512, 1024, 4096, 512};
        int f6[6] = {6, 4, 2, 8, 10, 12};
        int ts[7] = {0, 256, 512, 768, 1792, 5888, 6912};
        for (int i = 0; i < 6; i++) { ta.src[i] = s6[i]; ta.dst[i] = d6[i]; ta.R[i] = R6[i]; ta.C[i] = C6[i]; ta.flagidx[i] = f6[i]; }
        for (int i = 0; i < 7; i++) ta.tstart[i] = ts[i];
    }
    // fused: weight transposes (6912 blocks) + y->bf16 convert (32768 blocks)
    k_preproc<<<6912 + 32768, 256, 0, stream>>>(ta, flags, y, y_c);

    u16* attedpre = slotD;
    k_qkv_attn<<<512, 512, 0, stream>>>(y_c, WqT, WkT, WvT, par, maskb, attedpre);

    u16* mergeout = slotA;
    k_gemm_std<false><<<dim3(8, 64), 256, 0, stream>>>(attedpre, 1024, WmT, 1024, p_bm, mergeout, 1024, 1024);

    u16* y1 = slotB;
    k_ln<0><<<8192, 256, 0, stream>>>(y_c, mergeout, p_g1, p_be1, y1, nullptr);

    u16* h1 = Pbig;
    k_gemm_std<true><<<dim3(32, 64), 256, 0, stream>>>(y1, 1024, W1T, 1024, p_b1, h1, 4096, 1024);

    u16* ffout = slotC;
    k_gemm_ffn2<<<dim3(8, 64), 256, 0, stream>>>(h1, W2T, p_b2, ffout);

    k_ln<1><<<8192, 256, 0, stream>>>(y1, ffout, p_g2, p_be2, d_out, flags + 0);
}

// Round 11
// 387.224 us; speedup vs baseline: 1.1204x; 1.0525x over previous
//
#include <hip/hip_runtime.h>
#include <stdint.h>

typedef unsigned short u16;
using us8   = __attribute__((ext_vector_type(8))) unsigned short;
using us4   = __attribute__((ext_vector_type(4))) unsigned short;
using bf16x8 = __attribute__((ext_vector_type(8))) __bf16;
using f32x4 = __attribute__((ext_vector_type(4))) float;

#define DEV static __device__ __forceinline__

DEV float bf2f(u16 u) { union { uint32_t i; float f; } v; v.i = (uint32_t)u << 16; return v.f; }
DEV u16 f2bf(float f) {
    union { float f; uint32_t i; } v; v.f = f;
    uint32_t u = v.i;
    return (u16)((u + 0x7FFFu + ((u >> 16) & 1u)) >> 16);
}

// async global->LDS 16B copy: lane l writes LDS at (uniform base) + l*16B.
DEV void async16(const u16* g, u16* ldsbase)
{
    __builtin_amdgcn_global_load_lds((const __attribute__((address_space(1))) void*)g,
                                     (__attribute__((address_space(3))) void*)ldsbase, 16, 0, 0);
}

// ---------------------------------------------------------------------------
// Fused dtype detection: 18 blocks, one per input tensor. (round-8 form)
// ---------------------------------------------------------------------------
struct DetectArgs { const void* p[18]; int nw[18]; };

__global__ __launch_bounds__(256) void k_detect_all(DetectArgs a, int* flags)
{
    const int b = blockIdx.x;
    const int t = threadIdx.x;
    __shared__ int cnt[4];
    if (t < 4) cnt[t] = 0;
    __syncthreads();
    if (b == 1) {
        const uint8_t* m = (const uint8_t*)a.p[1];
        int c0 = 0, c1 = 0, c2 = 0, c3 = 0;
        for (int i = t; i < 4096; i += 256) {
            uint8_t v = m[i];
            int mod = i & 3;
            if (v == 0x3F && mod == 1) c0++;
            if (v == 0x3F && mod == 3) c1++;
            if (v == 1 && mod != 0) c2++;
            if (v == 1 && mod == 0) c3++;
        }
        atomicAdd(&cnt[0], c0); atomicAdd(&cnt[1], c1); atomicAdd(&cnt[2], c2); atomicAdd(&cnt[3], c3);
        __syncthreads();
        if (t == 0) {
            int mf;
            if (cnt[0] > 0) mf = 2;
            else if (cnt[1] > 0) mf = 3;
            else if (cnt[2] > 0) mf = 0;
            else if (cnt[3] > 0) mf = 1;
            else mf = 0;
            flags[1] = mf;
        }
    } else {
        const u16* p = (const u16*)a.p[b];
        int nw = a.nw[b];
        int nze = 0, pe = 0, nzo = 0;
        for (int i = t; i < nw; i += 256) {
            u16 w = p[i];
            if (w == 0) continue;
            int e = (w >> 7) & 0xFF;
            bool pl = (e >= 90 && e <= 140);
            if ((i & 1) == 0) { nze++; if (pl) pe++; }
            else nzo++;
        }
        atomicAdd(&cnt[0], nze); atomicAdd(&cnt[1], pe); atomicAdd(&cnt[2], nzo);
        __syncthreads();
        if (t == 0) {
            int f;
            if (cnt[0] > 0)      f = (cnt[1] * 10 >= cnt[0] * 6) ? 2 : 3;
            else if (cnt[2] > 0) f = 3;
            else                 f = 2;
            flags[b] = f;
        }
    }
}

__global__ __launch_bounds__(256) void k_expand_mask(const void* mask, const int* flag, float* mb)
{
    int i = blockIdx.x * 256 + threadIdx.x;
    if (i >= 4096) return;
    int f = *flag;
    bool on;
    if (f == 0)      on = ((const uint8_t*)mask)[i]  != 0;
    else if (f == 1) on = ((const int*)mask)[i]      != 0;
    else if (f == 2) on = ((const u16*)mask)[i]      != 0;
    else             on = ((const uint32_t*)mask)[i] != 0;
    mb[i] = on ? -1e9f : 0.0f;
}

// Vectorized y -> bf16 conversion: 8 elems/thread (G13 — scalar bf16/f32
// loads are ~2-2.5x slower; 16-32 B/lane is the coalescing sweet spot).
__global__ __launch_bounds__(256) void k_convert_bf(const void* src, u16* dst, int n, const int* flag)
{
    int i = (blockIdx.x * 256 + threadIdx.x) * 8;
    if (i >= n) return;
    if (*flag == 2) {
        *(us8*)(dst + i) = *(const us8*)((const u16*)src + i);
    } else {
        const float* s = (const float*)src + i;
        float4 va = *(const float4*)s;
        float4 vb = *(const float4*)(s + 4);
        us8 o;
        o[0] = f2bf(va.x); o[1] = f2bf(va.y); o[2] = f2bf(va.z); o[3] = f2bf(va.w);
        o[4] = f2bf(vb.x); o[5] = f2bf(vb.y); o[6] = f2bf(vb.z); o[7] = f2bf(vb.w);
        *(us8*)(dst + i) = o;
    }
}

// ---------------------------------------------------------------------------
// Fused LDS-tiled weight transposes (round-8 form)
// ---------------------------------------------------------------------------
struct TransArgs { const void* src[6]; u16* dst[6]; int R[6]; int C[6]; int flagidx[6]; int tstart[7]; };

__global__ __launch_bounds__(256) void k_transpose_all(TransArgs a, const int* flags)
{
    const int tb = blockIdx.x;
    int s = 0;
    while (tb >= a.tstart[s + 1]) s++;
    const int lt = tb - a.tstart[s];
    const int R = a.R[s], C = a.C[s];
    const int tilesX = C >> 5;
    const int ti = lt / tilesX, tj = lt - ti * tilesX;
    const int r0 = ti * 32, c0 = tj * 32;
    const bool isbf = (flags[a.flagidx[s]] == 2);
    const int t = threadIdx.x;
    const int j = t & 31, i0 = t >> 5;
    __shared__ u16 tile[32][33];
#pragma unroll
    for (int p = 0; p < 4; p++) {
        int r = r0 + i0 + p * 8;
        size_t idx = (size_t)r * C + c0 + j;
        u16 v = isbf ? ((const u16*)a.src[s])[idx] : f2bf(((const float*)a.src[s])[idx]);
        tile[i0 + p * 8][j] = v;
    }
    __syncthreads();
    u16* dst = a.dst[s];
#pragma unroll
    for (int p = 0; p < 4; p++) {
        int c = i0 + p * 8;
        dst[(size_t)(c0 + c) * R + r0 + j] = tile[j][c];
    }
}

// ---------------------------------------------------------------------------
// Fused param converts (round-8 form)
// ---------------------------------------------------------------------------
struct ConvArgs { const void* src[10]; int flagidx[10]; int off[10]; int n[10]; };

__global__ __launch_bounds__(256) void k_convert_params(ConvArgs a, const int* flags, float* par)
{
    int i = blockIdx.x * 256 + threadIdx.x;
    if (i >= 11264) return;
    int s = 0;
    while (s < 9 && i >= a.off[s] + a.n[s]) s++;
    int j = i - a.off[s];
    float v;
    if (flags[a.flagidx[s]] == 2) v = bf2f(((const u16*)a.src[s])[j]);
    else                          v = ((const float*)a.src[s])[j];
    par[i] = v;
}

// ---------------------------------------------------------------------------
// MFMA GEMM core, BK=64, async global->LDS staging with XOR-swizzled layout.
// C(M x N) = A(M x K, lda) * Bt(N x K, ldb)^T. fp32 accum. 256 threads.
// ---------------------------------------------------------------------------
template<int BM, int BN, int WR, int WC, int TM, int TN>
DEV void gemm_tile(const u16* __restrict__ A, int lda,
                   const u16* __restrict__ Bt, int ldb, int K,
                   u16* As, u16* Bs, f32x4 (&acc)[TM][TN])
{
    const int t = threadIdx.x;
    const int lane = t & 63;
    const int wave = t >> 6;
    const int wr = wave / WC;
    const int wc = wave % WC;
    const int m16 = lane & 15;
    const int quad = lane >> 4;
    const int lr8 = lane >> 3;                 // 0..7 row within 8-row chunk
    const int lsw = (((lane & 7) ^ lr8) << 3); // swizzled col offset (elements)

#pragma unroll
    for (int i = 0; i < TM; i++)
#pragma unroll
        for (int j = 0; j < TN; j++) {
            acc[i][j][0] = 0.f; acc[i][j][1] = 0.f; acc[i][j][2] = 0.f; acc[i][j][3] = 0.f;
        }

    for (int kb = 0; kb < K; kb += 64) {
#pragma unroll
        for (int i = 0; i < BM / 32; i++) {
            int chunk = wave * (BM / 32) + i;
            int r = chunk * 8 + lr8;
            async16(A + (size_t)r * lda + kb + lsw, As + chunk * 512);
        }
#pragma unroll
        for (int i = 0; i < BN / 32; i++) {
            int chunk = wave * (BN / 32) + i;
            int r = chunk * 8 + lr8;
            async16(Bt + (size_t)r * ldb + kb + lsw, Bs + chunk * 512);
        }
        __syncthreads();   // drains vmcnt (incl. global_load_lds) before LDS reads
#pragma unroll
        for (int ks = 0; ks < 2; ks++) {
            bf16x8 af[TM], bfr[TN];
#pragma unroll
            for (int i = 0; i < TM; i++) {
                int row = wr * TM * 16 + i * 16 + m16;
                int jq = ks * 4 + quad;
                af[i] = *(const bf16x8*)(As + row * 64 + ((jq ^ (row & 7)) << 3));
            }
#pragma unroll
            for (int j = 0; j < TN; j++) {
                int row = wc * TN * 16 + j * 16 + m16;
                int jq = ks * 4 + quad;
                bfr[j] = *(const bf16x8*)(Bs + row * 64 + ((jq ^ (row & 7)) << 3));
            }
#pragma unroll
            for (int i = 0; i < TM; i++)
#pragma unroll
                for (int j = 0; j < TN; j++)
                    acc[i][j] = __builtin_amdgcn_mfma_f32_16x16x32_bf16(af[i], bfr[j], acc[i][j], 0, 0, 0);
        }
        __syncthreads();
    }
}

template<bool RELU>
__global__ __launch_bounds__(256) void k_gemm_std(const u16* __restrict__ A, int lda,
                                                  const u16* __restrict__ Bt, int ldb,
                                                  const float* __restrict__ bias,
                                                  u16* __restrict__ C, int ldc, int K)
{
    __shared__ __align__(16) u16 As[128 * 64];
    __shared__ __align__(16) u16 Bs[128 * 64];
    const u16* Ab = A + (size_t)blockIdx.y * 128 * lda;
    const u16* Bb = Bt + (size_t)blockIdx.x * 128 * ldb;
    f32x4 acc[4][4];
    gemm_tile<128, 128, 2, 2, 4, 4>(Ab, lda, Bb, ldb, K, As, Bs, acc);

    const int t = threadIdx.x, lane = t & 63, wave = t >> 6;
    const int wr = wave >> 1, wc = wave & 1, m16 = lane & 15, quad = lane >> 4;
    const size_t rowBase = (size_t)blockIdx.y * 128 + wr * 64;
    const int colBase = blockIdx.x * 128 + wc * 64;
#pragma unroll
    for (int tm = 0; tm < 4; tm++)
#pragma unroll
        for (int tn = 0; tn < 4; tn++) {
            int col = colBase + tn * 16 + m16;
            float bv = bias ? bias[col] : 0.f;
#pragma unroll
            for (int r = 0; r < 4; r++) {
                size_t row = rowBase + tm * 16 + quad * 4 + r;
                float v = acc[tm][tn][r] + bv;
                if (RELU) v = fmaxf(v, 0.f);
                C[row * (size_t)ldc + col] = f2bf(v);
            }
        }
}

// Fused grouped FFN2: grid (8, 64). x -> (g = x>>2, xn = x&3). (round-8 form)
__global__ __launch_bounds__(256) void k_gemm_ffn2(const u16* __restrict__ h1,
                                                   const u16* __restrict__ W2T,
                                                   const float* __restrict__ b2,
                                                   u16* __restrict__ out)
{
    __shared__ __align__(16) u16 As[128 * 64];
    __shared__ __align__(16) u16 Bs[128 * 64];
    const int xi = blockIdx.x;
    const int g = xi >> 2, xn = xi & 3;
    const u16* Ab = h1 + (size_t)blockIdx.y * 128 * 4096 + g * 2048;
    const u16* Bb = W2T + (size_t)xn * 128 * 2048;
    f32x4 acc[4][4];
    gemm_tile<128, 128, 2, 2, 4, 4>(Ab, 4096, Bb, 2048, 2048, As, Bs, acc);

    const int t = threadIdx.x, lane = t & 63, wave = t >> 6;
    const int wr = wave >> 1, wc = wave & 1, m16 = lane & 15, quad = lane >> 4;
    const size_t rowBase = (size_t)blockIdx.y * 128 + wr * 64;
    const int colg = xn * 128 + wc * 64;
#pragma unroll
    for (int tm = 0; tm < 4; tm++)
#pragma unroll
        for (int tn = 0; tn < 4; tn++) {
            int cg = colg + tn * 16 + m16;
            float bv = b2[cg];
#pragma unroll
            for (int r = 0; r < 4; r++) {
                size_t row = rowBase + tm * 16 + quad * 4 + r;
                out[row * 1024 + g * 512 + cg] = f2bf(acc[tm][tn][r] + bv);
            }
        }
}

// ---------------------------------------------------------------------------
// Mega-fused attention block: QKV projection + scores + softmax + P*V in ONE
// kernel. Grid 512, 512 threads = 8 waves. (round-8-verified v2)
// ---------------------------------------------------------------------------
__global__ __launch_bounds__(512, 2) void k_qkv_attn(const u16* __restrict__ y_c,
                                                     const u16* __restrict__ WqT,
                                                     const u16* __restrict__ WkT,
                                                     const u16* __restrict__ WvT,
                                                     const float* __restrict__ par,
                                                     const float* __restrict__ maskb,
                                                     u16* __restrict__ attedpre)
{
    __shared__ __align__(16) u16 smem[57344];   // 112 KB
    u16* Asb0 = smem;            // chunk even A (16384 u16)
    u16* Asb1 = smem + 16384;    // chunk odd  A
    u16* Wsb0 = smem + 32768;    // chunk even W: Wq|Wk|Wv (3 x 4096 u16)
    u16* Wsb1 = smem + 45056;    // chunk odd  W
    u16* Ks   = smem;            // phase2: 256x64 K   (aliases Asb0)
    u16* Vs   = smem + 16384;    // phase2: 64x256 V^T (aliases Asb1)
    u16* Pw8  = smem + 32768;    // Q-route + PV chunks: 8 x 2048 (aliases W bufs)

    // XCD group swizzle: wg%8 = XCD id, constant for the 8 hlow members of a
    // (bg,hbit) group. Bijective over [0,512).
    const int wg = blockIdx.x;
    const int grp = (wg >> 6) * 8 + (wg & 7);   // 0..63
    const int hlow = (wg >> 3) & 7;
    const int bg = grp >> 1, hbit = grp & 1;
    const int b = bg & 15, g = bg >> 4;
    const int t = threadIdx.x, lane = t & 63, wave = t >> 6;
    const int m16 = lane & 15, quad = lane >> 4;
    const int lr8 = lane >> 3;
    const int lsw = (((lane & 7) ^ lr8) << 3);

    // A rows: s-th row is y_c row b*512 + 2s + hbit, cols g*512.. -> stride 2048
    const u16* Yb = y_c + (size_t)(b * 512 + hbit) * 1024 + g * 512;

    f32x4 aq[2][4], ak[2][4], av[2][4];
#pragma unroll
    for (int i = 0; i < 2; i++)
#pragma unroll
        for (int j = 0; j < 4; j++) {
            aq[i][j][0]=0.f; aq[i][j][1]=0.f; aq[i][j][2]=0.f; aq[i][j][3]=0.f;
            ak[i][j][0]=0.f; ak[i][j][1]=0.f; ak[i][j][2]=0.f; ak[i][j][3]=0.f;
            av[i][j][0]=0.f; av[i][j][1]=0.f; av[i][j][2]=0.f; av[i][j][3]=0.f;
        }

    // stage chunk c (7 async16/wave: 4 A + 3 W) into buf[c&1]
    auto stage = [&](int c) {
        const int kb = c * 64;
        u16* As_ = (c & 1) ? Asb1 : Asb0;
        u16* Ws_ = (c & 1) ? Wsb1 : Wsb0;
#pragma unroll
        for (int i = 0; i < 4; i++) {
            int chunk = wave * 4 + i;
            int srow = chunk * 8 + lr8;
            async16(Yb + (size_t)srow * 2048 + kb + lsw, As_ + chunk * 512);
        }
        int row = wave * 8 + lr8;
        const size_t woff = (size_t)(hlow * 64 + row) * 512 + kb + lsw;
        async16(WqT + woff, Ws_ + wave * 512);
        async16(WkT + woff, Ws_ + 4096 + wave * 512);
        async16(WvT + woff, Ws_ + 8192 + wave * 512);
    };

    // ---- phase 1: projections over 8 K-chunks, dbuf + counted vmcnt ----
    stage(0);
    for (int c = 0; c < 8; ++c) {
        if (c + 1 < 8) {
            stage(c + 1);                                    // 7 newer in flight
            asm volatile("s_waitcnt vmcnt(7)" ::: "memory"); // chunk c landed
        } else {
            asm volatile("s_waitcnt vmcnt(0)" ::: "memory");
        }
        asm volatile("s_barrier" ::: "memory");
        const u16* As_ = (c & 1) ? Asb1 : Asb0;
        const u16* Ws_ = (c & 1) ? Wsb1 : Wsb0;
#pragma unroll
        for (int ks = 0; ks < 2; ks++) {
            const int jq = ks * 4 + quad;
            bf16x8 af[2];
#pragma unroll
            for (int mt = 0; mt < 2; mt++) {
                int row = wave * 32 + mt * 16 + m16;
                af[mt] = *(const bf16x8*)(As_ + row * 64 + ((jq ^ (row & 7)) << 3));
            }
#pragma unroll
            for (int tn = 0; tn < 4; tn++) {
                int rowb = tn * 16 + m16;
                int offb = rowb * 64 + ((jq ^ (rowb & 7)) << 3);
                bf16x8 wq = *(const bf16x8*)(Ws_ + offb);
                bf16x8 wk = *(const bf16x8*)(Ws_ + 4096 + offb);
                bf16x8 wv = *(const bf16x8*)(Ws_ + 8192 + offb);
#pragma unroll
                for (int mt = 0; mt < 2; mt++) {
                    aq[mt][tn] = __builtin_amdgcn_mfma_f32_16x16x32_bf16(af[mt], wq, aq[mt][tn], 0, 0, 0);
                    ak[mt][tn] = __builtin_amdgcn_mfma_f32_16x16x32_bf16(af[mt], wk, ak[mt][tn], 0, 0, 0);
                    av[mt][tn] = __builtin_amdgcn_mfma_f32_16x16x32_bf16(af[mt], wv, av[mt][tn], 0, 0, 0);
                }
            }
        }
        asm volatile("s_barrier" ::: "memory");   // buf[c&1] readers done
    }

    // ---- projection epilogues (post final barrier: all phase-1 LDS dead) ----
    float bQ[4], bK[4], bV[4];
#pragma unroll
    for (int tn = 0; tn < 4; tn++) {
        int c0 = hlow * 64 + tn * 16 + m16;
        bQ[tn] = par[c0]; bK[tn] = par[512 + c0]; bV[tn] = par[1024 + c0];
    }
    u16* Qw = Pw8 + wave * 2048;   // per-wave 32x64 routing chunk
#pragma unroll
    for (int tm = 0; tm < 2; tm++)
#pragma unroll
        for (int tn = 0; tn < 4; tn++) {
            int dh = tn * 16 + m16;
#pragma unroll
            for (int r = 0; r < 4; r++) {
                int sl = tm * 16 + quad * 4 + r;          // local s 0..31
                int s_ = wave * 32 + sl;                  // global s 0..255
                // K[s][dh] -> Ks, gemm swizzle keyed on s
                Ks[s_ * 64 + ((((dh >> 3) ^ (s_ & 7)) << 3) | (dh & 7))] = f2bf(ak[tm][tn][r] + bK[tn]);
                // V[s][dh] -> Vs[dh][s], PV slot map keyed on (s>>3, dh)
                {
                    int j = s_ >> 3;
                    int slot = (j & 24) | ((j & 7) ^ (dh & 7));
                    Vs[dh * 256 + slot * 8 + (s_ & 7)] = f2bf(av[tm][tn][r] + bV[tn]);
                }
                // Q -> per-wave chunk (C-layout -> A-layout routing)
                Qw[sl * 64 + ((((dh >> 3) ^ (sl & 7)) << 3) | (dh & 7))] = f2bf(aq[tm][tn][r] + bQ[tn]);
            }
        }
    // read Q back as A-frags (wave-private, compiler orders ds write->read)
    bf16x8 qf[2][2];
#pragma unroll
    for (int mt = 0; mt < 2; mt++)
#pragma unroll
        for (int ks = 0; ks < 2; ks++) {
            int row = mt * 16 + m16;
            int jq = ks * 4 + quad;
            qf[mt][ks] = *(const bf16x8*)(Qw + row * 64 + ((jq ^ (row & 7)) << 3));
        }
    float mb[16];
#pragma unroll
    for (int nt = 0; nt < 16; nt++) mb[nt] = maskb[b * 256 + nt * 16 + m16];

    __syncthreads();   // Ks/Vs visible to all waves

    // ---- S = Q K^T ----
    f32x4 s[2][16];
#pragma unroll
    for (int mt = 0; mt < 2; mt++)
#pragma unroll
        for (int nt = 0; nt < 16; nt++) { s[mt][nt][0]=0.f; s[mt][nt][1]=0.f; s[mt][nt][2]=0.f; s[mt][nt][3]=0.f; }
#pragma unroll
    for (int ks = 0; ks < 2; ks++) {
        int jq = ks * 4 + quad;
#pragma unroll
        for (int nt = 0; nt < 16; nt++) {
            int row = nt * 16 + m16;
            bf16x8 kf = *(const bf16x8*)(Ks + row * 64 + ((jq ^ (row & 7)) << 3));
#pragma unroll
            for (int mt = 0; mt < 2; mt++)
                s[mt][nt] = __builtin_amdgcn_mfma_f32_16x16x32_bf16(qf[mt][ks], kf, s[mt][nt], 0, 0, 0);
        }
    }

    // ---- softmax, fully in-wave ----
    float rinv[2][4];
#pragma unroll
    for (int mt = 0; mt < 2; mt++)
#pragma unroll
        for (int r = 0; r < 4; r++) {
            float mm = -3.0e38f;
#pragma unroll
            for (int nt = 0; nt < 16; nt++) {
                float v = s[mt][nt][r] * 0.125f + mb[nt];
                s[mt][nt][r] = v;
                mm = fmaxf(mm, v);
            }
            mm = fmaxf(mm, __shfl_xor(mm, 1));
            mm = fmaxf(mm, __shfl_xor(mm, 2));
            mm = fmaxf(mm, __shfl_xor(mm, 4));
            mm = fmaxf(mm, __shfl_xor(mm, 8));
            float ss = 0.f;
#pragma unroll
            for (int nt = 0; nt < 16; nt++) {
                float e = __expf(s[mt][nt][r] - mm);
                s[mt][nt][r] = e;
                ss += e;
            }
            ss += __shfl_xor(ss, 1);
            ss += __shfl_xor(ss, 2);
            ss += __shfl_xor(ss, 4);
            ss += __shfl_xor(ss, 8);
            rinv[mt][r] = 1.0f / ss;
        }

    // ---- ctx = P V : route P chunks through the per-wave LDS chunk ----
    f32x4 ctx[2][4];
#pragma unroll
    for (int mt = 0; mt < 2; mt++)
#pragma unroll
        for (int dt = 0; dt < 4; dt++) { ctx[mt][dt][0]=0.f; ctx[mt][dt][1]=0.f; ctx[mt][dt][2]=0.f; ctx[mt][dt][3]=0.f; }

#pragma unroll
    for (int kc = 0; kc < 4; kc++) {
#pragma unroll
        for (int mt = 0; mt < 2; mt++)
#pragma unroll
            for (int nl = 0; nl < 4; nl++) {
                int nt = kc * 4 + nl;
#pragma unroll
                for (int r = 0; r < 4; r++) {
                    int row = mt * 16 + quad * 4 + r;
                    int col = nl * 16 + m16;
                    int j = col >> 3, e = col & 7;
                    Qw[row * 64 + (((j ^ (row & 7)) << 3) | e)] = f2bf(s[mt][nt][r] * rinv[mt][r]);
                }
            }
#pragma unroll
        for (int ks = 0; ks < 2; ks++) {
            int jq = ks * 4 + quad;
            bf16x8 pf[2];
#pragma unroll
            for (int mt = 0; mt < 2; mt++) {
                int row = mt * 16 + m16;
                pf[mt] = *(const bf16x8*)(Qw + row * 64 + ((jq ^ (row & 7)) << 3));
            }
#pragma unroll
            for (int dt = 0; dt < 4; dt++) {
                int d = dt * 16 + m16;
                int j = kc * 8 + ks * 4 + quad;
                int slot = (j & 24) | ((j & 7) ^ (d & 7));
                bf16x8 vf = *(const bf16x8*)(Vs + d * 256 + slot * 8);
#pragma unroll
                for (int mt = 0; mt < 2; mt++)
                    ctx[mt][dt] = __builtin_amdgcn_mfma_f32_16x16x32_bf16(pf[mt], vf, ctx[mt][dt], 0, 0, 0);
            }
        }
    }

    // ---- scatter ctx into attedpre (B,L,H): l = 2s+hbit, col = g*512+hlow*64+dh ----
    const int cBase = g * 512 + hlow * 64;
#pragma unroll
    for (int mt = 0; mt < 2; mt++)
#pragma unroll
        for (int dt = 0; dt < 4; dt++) {
            int dh = dt * 16 + m16;
#pragma unroll
            for (int r = 0; r < 4; r++) {
                int sI = wave * 32 + mt * 16 + quad * 4 + r;
                int l = 2 * sI + hbit;
                attedpre[((size_t)b * 512 + l) * 1024 + cBase + dh] = f2bf(ctx[mt][dt][r]);
            }
        }
}

// out = LN(x1 + x2) * gamma + beta over D=1024; one block per row.
template<int FINAL>
__global__ __launch_bounds__(256) void k_ln(const u16* __restrict__ x1, const u16* __restrict__ x2,
                                            const float* __restrict__ gamma, const float* __restrict__ beta,
                                            void* __restrict__ outv, const int* __restrict__ yflag)
{
    const size_t row = blockIdx.x;
    const int t = threadIdx.x;
    us4 a = *(const us4*)(x1 + row * 1024 + t * 4);
    us4 b = *(const us4*)(x2 + row * 1024 + t * 4);
    float v[4]; float s = 0.f, s2 = 0.f;
#pragma unroll
    for (int i = 0; i < 4; i++) { v[i] = bf2f(a[i]) + bf2f(b[i]); s += v[i]; s2 += v[i] * v[i]; }
#pragma unroll
    for (int off = 32; off > 0; off >>= 1) { s += __shfl_xor(s, off); s2 += __shfl_xor(s2, off); }
    __shared__ float red[8];
    const int lane = t & 63, wave = t >> 6;
    if (lane == 0) { red[wave] = s; red[wave + 4] = s2; }
    __syncthreads();
    s = red[0] + red[1] + red[2] + red[3];
    s2 = red[4] + red[5] + red[6] + red[7];
    float mean = s * (1.0f / 1024.0f);
    float var = fmaxf(s2 * (1.0f / 1024.0f) - mean * mean, 0.0f);
    float rs = rsqrtf(var + 1e-6f);
    float o[4];
#pragma unroll
    for (int i = 0; i < 4; i++) {
        int c = t * 4 + i;
        o[i] = (v[i] - mean) * rs * gamma[c] + beta[c];
    }
    bool f32out = FINAL && yflag && (*yflag == 3);
    if (f32out) {
        float* out = (float*)outv;
#pragma unroll
        for (int i = 0; i < 4; i++) out[row * 1024 + t * 4 + i] = o[i];
    } else {
        u16* out = (u16*)outv;
        us4 ov;
#pragma unroll
        for (int i = 0; i < 4; i++) ov[i] = f2bf(o[i]);
        *(us4*)(out + row * 1024 + t * 4) = ov;
    }
}

// ---------------------------------------------------------------------------
extern "C" void kernel_launch(void* const* d_in, const int* in_sizes, int n_in,
                              void* d_out, int out_size, void* d_ws, size_t ws_size,
                              hipStream_t stream)
{
    (void)in_sizes; (void)n_in; (void)out_size; (void)ws_size;
    const void* y    = d_in[0];
    const void* mask = d_in[1];
    const void* Wv = d_in[2];  const void* bv = d_in[3];
    const void* Wk = d_in[4];  const void* bk = d_in[5];
    const void* Wq = d_in[6];  const void* bq = d_in[7];
    const void* Wm = d_in[8];  const void* bm = d_in[9];
    const void* W1 = d_in[10]; const void* b1 = d_in[11];
    const void* W2 = d_in[12]; const void* b2 = d_in[13];
    const void* g1 = d_in[14]; const void* be1 = d_in[15];
    const void* g2 = d_in[16]; const void* be2 = d_in[17];

    char* ws = (char*)d_ws;
    size_t off = 0;
    auto alloc = [&](size_t bytes) { void* p = ws + off; off = (off + bytes + 255) & ~(size_t)255; return p; };

    int*   flags = (int*)alloc(32 * 4);
    float* maskb = (float*)alloc(16 * 256 * 4);
    float* par   = (float*)alloc(11264 * 4);
    u16* WqT  = (u16*)alloc((size_t)262144 * 2);
    u16* WkT  = (u16*)alloc((size_t)262144 * 2);
    u16* WvT  = (u16*)alloc((size_t)262144 * 2);
    u16* WmT  = (u16*)alloc((size_t)1048576 * 2);
    u16* W1T  = (u16*)alloc((size_t)4194304 * 2);
    u16* W2T  = (u16*)alloc((size_t)1048576 * 2);
    u16* y_c  = (u16*)alloc((size_t)8388608 * 2);
    u16* slotA = (u16*)alloc((size_t)8388608 * 2);   // mergeout
    u16* slotB = (u16*)alloc((size_t)8388608 * 2);   // y1
    u16* slotC = (u16*)alloc((size_t)8388608 * 2);   // ffout
    u16* slotD = (u16*)alloc((size_t)8388608 * 2);   // attedpre
    u16* Pbig  = (u16*)alloc((size_t)33554432 * 2);  // h1 (64 MB region)

    float* p_bm  = par + 1536;
    float* p_b1  = par + 2560;
    float* p_b2  = par + 6656;
    float* p_g1  = par + 7168;
    float* p_be1 = par + 8192;
    float* p_g2  = par + 9216;
    float* p_be2 = par + 10240;

    DetectArgs da;
    {
        const void* srcs[18] = {y, mask, Wv, bv, Wk, bk, Wq, bq, Wm, bm, W1, b1, W2, b2, g1, be1, g2, be2};
        const int   nele[18] = {8388608, 4096, 262144, 512, 262144, 512, 262144, 512, 1048576, 1024,
                                4194304, 4096, 1048576, 512, 1024, 1024, 1024, 1024};
        for (int i = 0; i < 18; i++) { da.p[i] = srcs[i]; da.nw[i] = nele[i] < 4096 ? nele[i] : 4096; }
    }
    k_detect_all<<<18, 256, 0, stream>>>(da, flags);

    k_expand_mask<<<16, 256, 0, stream>>>(mask, flags + 1, maskb);
    k_convert_bf<<<4096, 256, 0, stream>>>(y, y_c, 8388608, flags + 0);

    TransArgs ta;
    {
        const void* s6[6] = {Wq, Wk, Wv, Wm, W1, W2};
        u16* d6[6] = {WqT, WkT, WvT, WmT, W1T, W2T};
        int R6[6] = {512, 512, 512, 1024, 1024, 2048};
        int C6[6] = {512, 512, 512, 1024, 4096, 512};
        int f6[6] = {6, 4, 2, 8, 10, 12};
        int ts[7] = {0, 256, 512, 768, 1792, 5888, 6912};
        for (int i = 0; i < 6; i++) { ta.src[i] = s6[i]; ta.dst[i] = d6[i]; ta.R[i] = R6[i]; ta.C[i] = C6[i]; ta.flagidx[i] = f6[i]; }
        for (int i = 0; i < 7; i++) ta.tstart[i] = ts[i];
    }
    k_transpose_all<<<6912, 256, 0, stream>>>(ta, flags);

    ConvArgs ca;
    {
        const void* s10[10] = {bq, bk, bv, bm, b1, b2, g1, be1, g2, be2};
        int f10[10] = {7, 5, 3, 9, 11, 13, 14, 15, 16, 17};
        int o10[10] = {0, 512, 1024, 1536, 2560, 6656, 7168, 8192, 9216, 10240};
        int n10[10] = {512, 512, 512, 1024, 4096, 512, 1024, 1024, 1024, 1024};
        for (int i = 0; i < 10; i++) { ca.src[i] = s10[i]; ca.flagidx[i] = f10[i]; ca.off[i] = o10[i]; ca.n[i] = n10[i]; }
    }
    k_convert_params<<<44, 256, 0, stream>>>(ca, flags, par);

    u16* attedpre = slotD;
    k_qkv_attn<<<512, 512, 0, stream>>>(y_c, WqT, WkT, WvT, par, maskb, attedpre);

    u16* mergeout = slotA;
    k_gemm_std<false><<<dim3(8, 64), 256, 0, stream>>>(attedpre, 1024, WmT, 1024, p_bm, mergeout, 1024, 1024);

    u16* y1 = slotB;
    k_ln<0><<<8192, 256, 0, stream>>>(y_c, mergeout, p_g1, p_be1, y1, nullptr);

    u16* h1 = Pbig;
    k_gemm_std<true><<<dim3(32, 64), 256, 0, stream>>>(y1, 1024, W1T, 1024, p_b1, h1, 4096, 1024);

    u16* ffout = slotC;
    k_gemm_ffn2<<<dim3(8, 64), 256, 0, stream>>>(h1, W2T, p_b2, ffout);

    k_ln<1><<<8192, 256, 0, stream>>>(y1, ffout, p_g2, p_be2, d_out, flags + 0);
}